// Round 13
// baseline (1823.780 us; speedup 1.0000x reference)
//
#include <hip/hip_runtime.h>
#include <hip/hip_bf16.h>

#define D_MODEL 1024
#define H_MLP   4096
#define N_TOK   8192
#define T_SEQ   1024
#define NHEADS  16
#define HEAD_D  64
#define NEXPERT 8
#define LN_EPS  1e-5f
#define MAX_TILES 72
#define MAX_ROWS  (MAX_TILES * 256)
#define MB (1024 * 1024)

using f32x4 = __attribute__((ext_vector_type(4))) float;
using bh8   = __attribute__((ext_vector_type(8))) short;
typedef _Float16 h8 __attribute__((ext_vector_type(8)));

__device__ __forceinline__ unsigned short f2b(float f) {
  unsigned u = __float_as_uint(f);
  return (unsigned short)((u + 0x7FFFu + ((u >> 16) & 1u)) >> 16);
}
__device__ __forceinline__ float b2f(unsigned short h) {
  return __uint_as_float(((unsigned)h) << 16);
}
__device__ __forceinline__ void split16(float v, unsigned short& hi, unsigned short& lo) {
  const _Float16 h = (_Float16)v;
  const _Float16 l = (_Float16)(v - (float)h);
  hi = __builtin_bit_cast(unsigned short, h);
  lo = __builtin_bit_cast(unsigned short, l);
}
// global -> LDS async 16B copy. LDS dest: wave-uniform base + lane*16.
__device__ __forceinline__ void gll16(const unsigned short* g, unsigned short* lds) {
  __builtin_amdgcn_global_load_lds(
      (const __attribute__((address_space(1))) unsigned int*)(const void*)g,
      (__attribute__((address_space(3))) unsigned int*)(void*)lds, 16, 0, 0);
}

// ---------------- LayerNorm 1: f32 x -> f16 hi/lo h1 ----------------
__global__ __launch_bounds__(256) void ln1_kernel(
    const float* __restrict__ x, const float* __restrict__ g,
    const float* __restrict__ b, unsigned short* __restrict__ oh,
    unsigned short* __restrict__ ol) {
  const int t = blockIdx.x, tid = threadIdx.x;
  const float4 v = ((const float4*)(x + (size_t)t * D_MODEL))[tid];
  float s  = v.x + v.y + v.z + v.w;
  float sq = v.x * v.x + v.y * v.y + v.z * v.z + v.w * v.w;
  __shared__ float red[8];
  #pragma unroll
  for (int o = 32; o > 0; o >>= 1) { s += __shfl_down(s, o); sq += __shfl_down(sq, o); }
  if ((tid & 63) == 0) { red[tid >> 6] = s; red[4 + (tid >> 6)] = sq; }
  __syncthreads();
  s  = red[0] + red[1] + red[2] + red[3];
  sq = red[4] + red[5] + red[6] + red[7];
  const float mu = s * (1.0f / D_MODEL);
  const float var = sq * (1.0f / D_MODEL) - mu * mu;
  const float rs = 1.0f / sqrtf(var + LN_EPS);
  const float4 gv = ((const float4*)g)[tid];
  const float4 bv = ((const float4*)b)[tid];
  float4 o;
  o.x = (v.x - mu) * rs * gv.x + bv.x;
  o.y = (v.y - mu) * rs * gv.y + bv.y;
  o.z = (v.z - mu) * rs * gv.z + bv.z;
  o.w = (v.w - mu) * rs * gv.w + bv.w;
  ushort4 hs, ls;
  split16(o.x, hs.x, ls.x); split16(o.y, hs.y, ls.y);
  split16(o.z, hs.z, ls.z); split16(o.w, hs.w, ls.w);
  ((ushort4*)(oh + (size_t)t * D_MODEL))[tid] = hs;
  ((ushort4*)(ol + (size_t)t * D_MODEL))[tid] = ls;
}

// ------- split-f16 MFMA GEMM: C = A @ B^T + bias. A,B^T given as f16 hi/lo. -------
// Grid: x = column tile (fast, shares A-tile), y = row tile.
// MODE 0: C -> f16 hi/lo pair.  MODE 1: C -> f32 with +residual.
template<int MODE>
__global__ __launch_bounds__(256) void gemm_split_kernel(
    const unsigned short* __restrict__ Ah_g, const unsigned short* __restrict__ Al_g,
    const unsigned short* __restrict__ Bh_g, const unsigned short* __restrict__ Bl_g,
    const float* __restrict__ bias, const float* __restrict__ Rres,
    unsigned short* __restrict__ Ch, unsigned short* __restrict__ Cl,
    float* __restrict__ Cf, int M, int N, int K) {
  __shared__ unsigned short LAh[128 * 32], LAl[128 * 32];
  __shared__ unsigned short LBh[128 * 32], LBl[128 * 32];
  const int tid = threadIdx.x, lane = tid & 63, w = tid >> 6;
  const int bm = blockIdx.y * 128, bn = blockIdx.x * 128;
  const int wm = (w >> 1) * 64, wn = (w & 1) * 64;
  f32x4 acc[4][4];
  #pragma unroll
  for (int i = 0; i < 4; ++i)
    #pragma unroll
    for (int j = 0; j < 4; ++j) acc[i][j] = (f32x4){0.f, 0.f, 0.f, 0.f};
  const int lrow16 = lane >> 2, kq8 = (lane & 3) << 3;
  const int r0 = w * 16 + lrow16, r1 = 64 + w * 16 + lrow16;
  const size_t a0 = (size_t)(bm + r0) * K + kq8, a1 = (size_t)(bm + r1) * K + kq8;
  const size_t b0 = (size_t)(bn + r0) * K + kq8, b1 = (size_t)(bn + r1) * K + kq8;
  const int lb0 = (w * 16) * 32, lb1 = (64 + w * 16) * 32;
  const int lrow = lane & 15, lk = (lane >> 4) << 3;
  for (int k0 = 0; k0 < K; k0 += 32) {
    gll16(Ah_g + a0 + k0, &LAh[lb0]); gll16(Ah_g + a1 + k0, &LAh[lb1]);
    gll16(Al_g + a0 + k0, &LAl[lb0]); gll16(Al_g + a1 + k0, &LAl[lb1]);
    gll16(Bh_g + b0 + k0, &LBh[lb0]); gll16(Bh_g + b1 + k0, &LBh[lb1]);
    gll16(Bl_g + b0 + k0, &LBl[lb0]); gll16(Bl_g + b1 + k0, &LBl[lb1]);
    __syncthreads();
    h8 ah[4], al[4], bh[4], bl[4];
    #pragma unroll
    for (int i = 0; i < 4; ++i) {
      ah[i] = *(const h8*)&LAh[(wm + i * 16 + lrow) * 32 + lk];
      al[i] = *(const h8*)&LAl[(wm + i * 16 + lrow) * 32 + lk];
    }
    #pragma unroll
    for (int j = 0; j < 4; ++j) {
      bh[j] = *(const h8*)&LBh[(wn + j * 16 + lrow) * 32 + lk];
      bl[j] = *(const h8*)&LBl[(wn + j * 16 + lrow) * 32 + lk];
    }
    #pragma unroll
    for (int i = 0; i < 4; ++i)
      #pragma unroll
      for (int j = 0; j < 4; ++j) {
        acc[i][j] = __builtin_amdgcn_mfma_f32_16x16x32_f16(ah[i], bh[j], acc[i][j], 0, 0, 0);
        acc[i][j] = __builtin_amdgcn_mfma_f32_16x16x32_f16(ah[i], bl[j], acc[i][j], 0, 0, 0);
        acc[i][j] = __builtin_amdgcn_mfma_f32_16x16x32_f16(al[i], bh[j], acc[i][j], 0, 0, 0);
      }
    __syncthreads();
  }
  const int lc = lane & 15, lr4 = (lane >> 4) * 4;
  #pragma unroll
  for (int i = 0; i < 4; ++i)
    #pragma unroll
    for (int j = 0; j < 4; ++j) {
      const int col = bn + wn + j * 16 + lc;
      const float bsv = bias[col];
      #pragma unroll
      for (int qq = 0; qq < 4; ++qq) {
        const size_t row = (size_t)bm + wm + i * 16 + lr4 + qq;
        const size_t idx = row * N + col;
        const float v = acc[i][j][qq] + bsv;
        if (MODE == 0) {
          unsigned short hi, lo;
          split16(v, hi, lo);
          Ch[idx] = hi; Cl[idx] = lo;
        } else {
          Cf[idx] = v + Rres[idx];
        }
      }
    }
}

// ------------- V transpose: [B,T,H*64] f16 -> [B*H, 64, T] f16 -------------
__global__ __launch_bounds__(256) void vtrans_kernel(
    const unsigned short* __restrict__ src, unsigned short* __restrict__ dst) {
  __shared__ unsigned short tile[64][72];
  const int tid = threadIdx.x;
  const int t0 = blockIdx.x * 64, bh = blockIdx.y;
  const int b = bh >> 4, h = bh & 15;
  #pragma unroll
  for (int it = 0; it < 2; ++it) {
    const int sg = tid + it * 256;
    const int r = sg >> 3, s = sg & 7;
    *(uint4*)&tile[r][s * 8] =
        *(const uint4*)(src + ((size_t)b * T_SEQ + t0 + r) * D_MODEL + h * HEAD_D + s * 8);
  }
  __syncthreads();
  #pragma unroll
  for (int it = 0; it < 2; ++it) {
    const int sg = tid + it * 256;
    const int d = sg >> 3, s = sg & 7;
    unsigned short v8[8] __attribute__((aligned(16)));
    #pragma unroll
    for (int j = 0; j < 8; ++j) v8[j] = tile[s * 8 + j][d];
    *(uint4*)(dst + ((size_t)bh * HEAD_D + d) * T_SEQ + t0 + s * 8) = *(const uint4*)v8;
  }
}

// ---- causal flash attention v2: 8 waves, QB=128, KB=64, split-f16 MFMA ----
__global__ __launch_bounds__(512) void attn_mfma_kernel(
    const unsigned short* __restrict__ qh_g, const unsigned short* __restrict__ ql_g,
    const unsigned short* __restrict__ kh_g, const unsigned short* __restrict__ kl_g,
    const unsigned short* __restrict__ vth_g, const unsigned short* __restrict__ vtl_g,
    unsigned short* __restrict__ yh, unsigned short* __restrict__ yl) {
  __shared__ unsigned short Kh[64][72], Kl[64][72], Vh[64][72], Vl[64][72];
  __shared__ float Ps[8][16][36];   // per-wave P scratch, one 32-k half at a time
  const int tid = threadIdx.x, lane = tid & 63, w = tid >> 6;       // w = 0..7
  const int g = lane >> 4, c = lane & 15;
  const int qt = (int)gridDim.x - 1 - (int)blockIdx.x;              // big tiles first
  const int bh = blockIdx.y, b = bh >> 4, h = bh & 15;
  const size_t qrow0 = (size_t)b * T_SEQ + qt * 128;
  // Q fragments (tile-invariant), A-frag: row = c, k-chunk = g*8
  h8 aqh[2], aql[2];
  {
    const size_t rq = (qrow0 + w * 16 + c) * D_MODEL + h * HEAD_D + g * 8;
    aqh[0] = *(const h8*)(qh_g + rq);
    aqh[1] = *(const h8*)(qh_g + rq + 32);
    aql[0] = *(const h8*)(ql_g + rq);
    aql[1] = *(const h8*)(ql_g + rq + 32);
  }
  f32x4 oacc[4];
  #pragma unroll
  for (int i = 0; i < 4; ++i) oacc[i] = (f32x4){0.f, 0.f, 0.f, 0.f};
  float m[4] = {-3e38f, -3e38f, -3e38f, -3e38f};
  float l[4] = {0.f, 0.f, 0.f, 0.f};
  const int sgr = tid >> 3, sgs = tid & 7;   // 512 threads: one uint4 per buffer each
  const int nkt = 2 * qt + 2;
  for (int kt = 0; kt < nkt; ++kt) {
    const int kv0 = kt * 64;
    __syncthreads();
    {
      const size_t kb = ((size_t)b * T_SEQ + kv0 + sgr) * D_MODEL + h * HEAD_D + sgs * 8;
      const size_t vb = ((size_t)bh * HEAD_D + sgr) * T_SEQ + kv0 + sgs * 8;
      *(uint4*)&Kh[sgr][sgs * 8] = *(const uint4*)(kh_g + kb);
      *(uint4*)&Kl[sgr][sgs * 8] = *(const uint4*)(kl_g + kb);
      *(uint4*)&Vh[sgr][sgs * 8] = *(const uint4*)(vth_g + vb);
      *(uint4*)&Vl[sgr][sgs * 8] = *(const uint4*)(vtl_g + vb);
    }
    __syncthreads();
    // S = Q K^T (3-term split)
    f32x4 sv[4];
    __builtin_amdgcn_s_setprio(1);
    #pragma unroll
    for (int nt = 0; nt < 4; ++nt) {
      f32x4 s = {0.f, 0.f, 0.f, 0.f};
      #pragma unroll
      for (int ks = 0; ks < 2; ++ks) {
        const h8 bkh = *(const h8*)&Kh[nt * 16 + c][ks * 32 + g * 8];
        const h8 bkl = *(const h8*)&Kl[nt * 16 + c][ks * 32 + g * 8];
        s = __builtin_amdgcn_mfma_f32_16x16x32_f16(aqh[ks], bkh, s, 0, 0, 0);
        s = __builtin_amdgcn_mfma_f32_16x16x32_f16(aqh[ks], bkl, s, 0, 0, 0);
        s = __builtin_amdgcn_mfma_f32_16x16x32_f16(aql[ks], bkh, s, 0, 0, 0);
      }
      sv[nt] = s;
    }
    __builtin_amdgcn_s_setprio(0);
    // mask + scale + row max (row = q: g*4+qq; col = k: nt*16+c)
    float pm[4] = {-3e38f, -3e38f, -3e38f, -3e38f};
    #pragma unroll
    for (int nt = 0; nt < 4; ++nt)
      #pragma unroll
      for (int qq = 0; qq < 4; ++qq) {
        float sval = sv[nt][qq] * 0.125f;
        const int krow = kv0 + nt * 16 + c;
        const int qrow = qt * 128 + w * 16 + g * 4 + qq;
        sval = (krow <= qrow) ? sval : -3.0e38f;
        sv[nt][qq] = sval;
        pm[qq] = fmaxf(pm[qq], sval);
      }
    #pragma unroll
    for (int o = 1; o < 16; o <<= 1)
      #pragma unroll
      for (int qq = 0; qq < 4; ++qq) pm[qq] = fmaxf(pm[qq], __shfl_xor(pm[qq], o));
    float psum[4];
    #pragma unroll
    for (int qq = 0; qq < 4; ++qq) {
      const float mnew = fmaxf(m[qq], pm[qq]);
      const float sc = expf(m[qq] - mnew);
      m[qq] = mnew;
      l[qq] *= sc;
      #pragma unroll
      for (int dt = 0; dt < 4; ++dt) oacc[dt][qq] *= sc;
      psum[qq] = 0.f;
    }
    #pragma unroll
    for (int nt = 0; nt < 4; ++nt)
      #pragma unroll
      for (int qq = 0; qq < 4; ++qq) {
        const float p = expf(sv[nt][qq] - m[qq]);
        sv[nt][qq] = p;
        psum[qq] += p;
      }
    #pragma unroll
    for (int o = 1; o < 16; o <<= 1)
      #pragma unroll
      for (int qq = 0; qq < 4; ++qq) psum[qq] += __shfl_xor(psum[qq], o);
    #pragma unroll
    for (int qq = 0; qq < 4; ++qq) l[qq] += psum[qq];
    // PV in two k-halves: write half of P (per-wave LDS), read transposed, MFMA.
    #pragma unroll
    for (int half = 0; half < 2; ++half) {
      #pragma unroll
      for (int nt2 = 0; nt2 < 2; ++nt2)
        #pragma unroll
        for (int qq = 0; qq < 4; ++qq)
          Ps[w][g * 4 + qq][nt2 * 16 + c] = sv[half * 2 + nt2][qq];
      const float4 p0 = *(const float4*)&Ps[w][c][g * 8];
      const float4 p1 = *(const float4*)&Ps[w][c][g * 8 + 4];
      const float pv[8] = {p0.x, p0.y, p0.z, p0.w, p1.x, p1.y, p1.z, p1.w};
      h8 pah, pal;
      #pragma unroll
      for (int j = 0; j < 8; ++j) {
        const _Float16 hi = (_Float16)pv[j];
        pah[j] = hi;
        pal[j] = (_Float16)(pv[j] - (float)hi);
      }
      __builtin_amdgcn_s_setprio(1);
      #pragma unroll
      for (int dt = 0; dt < 4; ++dt) {
        const h8 bvh = *(const h8*)&Vh[dt * 16 + c][half * 32 + g * 8];
        const h8 bvl = *(const h8*)&Vl[dt * 16 + c][half * 32 + g * 8];
        oacc[dt] = __builtin_amdgcn_mfma_f32_16x16x32_f16(pah, bvh, oacc[dt], 0, 0, 0);
        oacc[dt] = __builtin_amdgcn_mfma_f32_16x16x32_f16(pah, bvl, oacc[dt], 0, 0, 0);
        oacc[dt] = __builtin_amdgcn_mfma_f32_16x16x32_f16(pal, bvh, oacc[dt], 0, 0, 0);
      }
      __builtin_amdgcn_s_setprio(0);
      if (half == 0) __builtin_amdgcn_sched_barrier(0);
    }
  }
  #pragma unroll
  for (int qq = 0; qq < 4; ++qq) {
    const float inv = 1.0f / l[qq];
    const size_t row = (qrow0 + w * 16 + g * 4 + qq) * D_MODEL + h * HEAD_D;
    #pragma unroll
    for (int dt = 0; dt < 4; ++dt) {
      unsigned short hi, lo;
      split16(oacc[dt][qq] * inv, hi, lo);
      yh[row + dt * 16 + c] = hi;
      yl[row + dt * 16 + c] = lo;
    }
  }
}

// ------------- LN2 + gate logits + top2 routing (f32) -------------
__global__ __launch_bounds__(256) void ln2_route_kernel(
    const float* __restrict__ x1, const float* __restrict__ g,
    const float* __restrict__ b, const float* __restrict__ gW,
    const float* __restrict__ gb, unsigned short* __restrict__ h2b,
    int2* __restrict__ tok_e, float2* __restrict__ tok_w, int* __restrict__ counts) {
  const int t = blockIdx.x, tid = threadIdx.x;
  const float4 v = ((const float4*)(x1 + (size_t)t * D_MODEL))[tid];
  float s  = v.x + v.y + v.z + v.w;
  float sq = v.x * v.x + v.y * v.y + v.z * v.z + v.w * v.w;
  __shared__ float red[8];
  __shared__ float lred[4][8];
  #pragma unroll
  for (int o = 32; o > 0; o >>= 1) { s += __shfl_down(s, o); sq += __shfl_down(sq, o); }
  if ((tid & 63) == 0) { red[tid >> 6] = s; red[4 + (tid >> 6)] = sq; }
  __syncthreads();
  s  = red[0] + red[1] + red[2] + red[3];
  sq = red[4] + red[5] + red[6] + red[7];
  const float mu = s * (1.0f / D_MODEL);
  const float var = sq * (1.0f / D_MODEL) - mu * mu;
  const float rs = 1.0f / sqrtf(var + LN_EPS);
  const float4 gv = ((const float4*)g)[tid];
  const float4 bv = ((const float4*)b)[tid];
  float4 hv;
  hv.x = (v.x - mu) * rs * gv.x + bv.x;
  hv.y = (v.y - mu) * rs * gv.y + bv.y;
  hv.z = (v.z - mu) * rs * gv.z + bv.z;
  hv.w = (v.w - mu) * rs * gv.w + bv.w;
  ushort4 hs;
  hs.x = f2b(hv.x); hs.y = f2b(hv.y); hs.z = f2b(hv.z); hs.w = f2b(hv.w);
  ((ushort4*)(h2b + (size_t)t * D_MODEL))[tid] = hs;
  float lg[8];
  const float* gwr = gW + (size_t)tid * 32;
  #pragma unroll
  for (int e = 0; e < 8; ++e)
    lg[e] = hv.x * gwr[e] + hv.y * gwr[8 + e] +
            hv.z * gwr[16 + e] + hv.w * gwr[24 + e];
  #pragma unroll
  for (int o = 32; o > 0; o >>= 1)
    #pragma unroll
    for (int e = 0; e < 8; ++e) lg[e] += __shfl_down(lg[e], o);
  if ((tid & 63) == 0)
    #pragma unroll
    for (int e = 0; e < 8; ++e) lred[tid >> 6][e] = lg[e];
  __syncthreads();
  if (tid == 0) {
    float L[8];
    #pragma unroll
    for (int e = 0; e < 8; ++e)
      L[e] = lred[0][e] + lred[1][e] + lred[2][e] + lred[3][e] + gb[e];
    int e0 = 0; float v0 = L[0];
    for (int e = 1; e < 8; ++e) if (L[e] > v0) { v0 = L[e]; e0 = e; }
    int e1 = (e0 == 0) ? 1 : 0; float v1 = L[e1];
    for (int e = 0; e < 8; ++e) if (e != e0 && L[e] > v1) { v1 = L[e]; e1 = e; }
    const float ew = expf(v1 - v0);
    const float inv = 1.0f / (1.0f + ew);
    tok_e[t] = make_int2(e0, e1);
    tok_w[t] = make_float2(inv, ew * inv);
    atomicAdd(&counts[e0], 1);
    atomicAdd(&counts[e1], 1);
  }
}

// ------------- routing bookkeeping (256-aligned expert segments) -------------
__global__ void route_offsets_kernel(const int* __restrict__ counts, int* __restrict__ off_al,
    int* __restrict__ ntiles, int* __restrict__ map_e, int* __restrict__ map_row) {
  if (threadIdx.x != 0 || blockIdx.x != 0) return;
  int off = 0, ti = 0;
  for (int e = 0; e < NEXPERT; ++e) {
    off_al[e] = off;
    const int tiles = (counts[e] + 255) >> 8;
    for (int j = 0; j < tiles; ++j) { map_e[ti] = e; map_row[ti] = off + (j << 8); ++ti; }
    off += tiles << 8;
  }
  off_al[NEXPERT] = off;
  ntiles[0] = ti;
}

__global__ __launch_bounds__(256) void place_kernel(
    const int2* __restrict__ tok_e, const int* __restrict__ off_al,
    int* __restrict__ cursors, int* __restrict__ list, int2* __restrict__ tok_pos) {
  const int t = blockIdx.x * 256 + threadIdx.x;
  if (t >= N_TOK) return;
  const int2 te = tok_e[t];
  const int p0 = off_al[te.x] + atomicAdd(&cursors[te.x], 1);
  const int p1 = off_al[te.y] + atomicAdd(&cursors[te.y], 1);
  list[p0] = t; list[p1] = t;
  tok_pos[t] = make_int2(p0, p1);
}

__global__ __launch_bounds__(256) void fill_pad_kernel(
    const int* __restrict__ counts, const int* __restrict__ off_al, int* __restrict__ list) {
  const int i = blockIdx.x * 256 + threadIdx.x;
  const int e = i >> 8, j = i & 255;
  if (e >= NEXPERT) return;
  const int start = off_al[e] + counts[e];
  if (start + j < off_al[e + 1]) list[start + j] = 0;
}

// ------------- f32 -> bf16 transpose (expert weights -> [N][K] layout) -------------
__global__ void transpose_cvt_kernel(
    const float* __restrict__ in, unsigned short* __restrict__ outp, int R, int C) {
  __shared__ float tile[32][33];
  const int e = blockIdx.z;
  const float* I = in + (size_t)e * R * C;
  unsigned short* O = outp + (size_t)e * R * C;
  const int c0 = blockIdx.x * 32, r0 = blockIdx.y * 32;
  const int tx = threadIdx.x, ty = threadIdx.y;
  #pragma unroll
  for (int j = 0; j < 32; j += 8)
    tile[ty + j][tx] = I[(size_t)(r0 + ty + j) * C + c0 + tx];
  __syncthreads();
  #pragma unroll
  for (int j = 0; j < 32; j += 8)
    O[(size_t)(c0 + ty + j) * R + r0 + tx] = f2b(tile[tx][ty + j]);
}

// ------------- f32 -> f16 hi/lo transpose (proj weights -> [N][K]) -------------
__global__ void transpose_cvt_f16_kernel(
    const float* __restrict__ in, unsigned short* __restrict__ oh,
    unsigned short* __restrict__ ol, int R, int C) {
  __shared__ float tile[32][33];
  const int c0 = blockIdx.x * 32, r0 = blockIdx.y * 32;
  const int tx = threadIdx.x, ty = threadIdx.y;
  #pragma unroll
  for (int j = 0; j < 32; j += 8)
    tile[ty + j][tx] = in[(size_t)(r0 + ty + j) * C + c0 + tx];
  __syncthreads();
  #pragma unroll
  for (int j = 0; j < 32; j += 8) {
    unsigned short hi, lo;
    split16(tile[tx][ty + j], hi, lo);
    oh[(size_t)(c0 + ty + j) * R + r0 + tx] = hi;
    ol[(size_t)(c0 + ty + j) * R + r0 + tx] = lo;
  }
}

// ------------- expert GEMM: bf16 MFMA 16x16x32, 256x128 tile, gll staging -------------
// BM=256 halves B-panel sweeps vs BM=128 (L2-fill traffic was the round-9/12 bound).
// 4 waves in 2x2: each wave owns 128x64 (acc[8][4]). Grid: x = col tile, y = M-tile.
template<int GELU_OUT, int GATHER>
__global__ __launch_bounds__(256) void moe_gemm_kernel(
    const unsigned short* __restrict__ Abase, const unsigned short* __restrict__ Bbase,
    const float* __restrict__ biasBase, unsigned short* __restrict__ midOut,
    float* __restrict__ fOut, const int* __restrict__ list,
    const int* __restrict__ map_e, const int* __restrict__ map_row,
    const int* __restrict__ ntiles_p, int K, int N) {
  const int mt = blockIdx.y;
  if (mt >= ntiles_p[0]) return;
  const int e = map_e[mt];
  const int row0 = map_row[mt];
  const int bn = blockIdx.x * 128;
  const unsigned short* Bp = Bbase + (size_t)e * (size_t)N * (size_t)K;
  const float* bias = biasBase + (size_t)e * N;
  __shared__ unsigned short As[256 * 32];   // 16 KB
  __shared__ unsigned short Bs[128 * 32];   // 8 KB
  const int tid = threadIdx.x, lane = tid & 63, wid = tid >> 6;
  const int wm = (wid >> 1) * 128, wn = (wid & 1) * 64;
  f32x4 acc[8][4];
  #pragma unroll
  for (int i = 0; i < 8; ++i)
    #pragma unroll
    for (int j = 0; j < 4; ++j) acc[i][j] = (f32x4){0.f, 0.f, 0.f, 0.f};
  const int lrow16 = lane >> 2, kq8 = (lane & 3) << 3;
  size_t arow[4];
  #pragma unroll
  for (int rr = 0; rr < 4; ++rr) {
    const int r = rr * 64 + wid * 16 + lrow16;
    if (GATHER) arow[rr] = (size_t)list[row0 + r] * (size_t)K + kq8;
    else        arow[rr] = (size_t)(row0 + r) * (size_t)K + kq8;
  }
  size_t brow[2];
  #pragma unroll
  for (int rr = 0; rr < 2; ++rr) {
    const int r = rr * 64 + wid * 16 + lrow16;
    brow[rr] = (size_t)(bn + r) * (size_t)K + kq8;
  }
  const int lrow = lane & 15, lk = (lane >> 4) << 3;
  for (int k0 = 0; k0 < K; k0 += 32) {
    #pragma unroll
    for (int rr = 0; rr < 4; ++rr)
      gll16(Abase + arow[rr] + k0, &As[(rr * 64 + wid * 16) * 32]);
    #pragma unroll
    for (int rr = 0; rr < 2; ++rr)
      gll16(Bp + brow[rr] + k0, &Bs[(rr * 64 + wid * 16) * 32]);
    __syncthreads();
    bh8 a[8], b[4];
    #pragma unroll
    for (int i = 0; i < 8; ++i) a[i] = *(const bh8*)&As[(wm + i * 16 + lrow) * 32 + lk];
    #pragma unroll
    for (int j = 0; j < 4; ++j) b[j] = *(const bh8*)&Bs[(wn + j * 16 + lrow) * 32 + lk];
    __builtin_amdgcn_s_setprio(1);
    #pragma unroll
    for (int i = 0; i < 8; ++i)
      #pragma unroll
      for (int j = 0; j < 4; ++j)
        acc[i][j] = __builtin_amdgcn_mfma_f32_16x16x32_bf16(a[i], b[j], acc[i][j], 0, 0, 0);
    __builtin_amdgcn_s_setprio(0);
    __syncthreads();
  }
  const int lc = lane & 15, lr4 = (lane >> 4) * 4;
  #pragma unroll
  for (int i = 0; i < 8; ++i)
    #pragma unroll
    for (int j = 0; j < 4; ++j) {
      const int col = bn + wn + j * 16 + lc;
      const float bsv = bias[col];
      #pragma unroll
      for (int qq = 0; qq < 4; ++qq) {
        const int rowl = wm + i * 16 + lr4 + qq;
        const size_t idx = (size_t)(row0 + rowl) * N + col;
        const float xv = acc[i][j][qq] + bsv;
        if (GELU_OUT) {
          const float gel = 0.5f * xv * (1.0f + erff(xv * 0.70710678118654752f));
          midOut[idx] = f2b(gel);
        } else {
          fOut[idx] = xv;
        }
      }
    }
}

// ------------- combine: out = x1 + w0*y[pos0] + w1*y[pos1], f32 out -------------
__global__ __launch_bounds__(256) void combine_kernel(
    const float* __restrict__ x1, const float* __restrict__ ylist,
    const int2* __restrict__ tok_pos, const float2* __restrict__ tok_w,
    float* __restrict__ outp) {
  const int t = blockIdx.x, tid = threadIdx.x;
  const int2 p = tok_pos[t];
  const float2 w = tok_w[t];
  const float4 a  = ((const float4*)(x1 + (size_t)t * D_MODEL))[tid];
  const float4 y0 = ((const float4*)(ylist + (size_t)p.x * D_MODEL))[tid];
  const float4 y1 = ((const float4*)(ylist + (size_t)p.y * D_MODEL))[tid];
  float4 o;
  o.x = a.x + w.x * y0.x + w.y * y1.x;
  o.y = a.y + w.x * y0.y + w.y * y1.y;
  o.z = a.z + w.x * y0.z + w.y * y1.z;
  o.w = a.w + w.x * y0.w + w.y * y1.w;
  ((float4*)(outp + (size_t)t * D_MODEL))[tid] = o;
}

extern "C" void kernel_launch(void* const* d_in, const int* in_sizes, int n_in,
                              void* d_out, int out_size, void* d_ws, size_t ws_size,
                              hipStream_t stream) {
  const float* x    = (const float*)d_in[0];
  const float* ln1g = (const float*)d_in[1];
  const float* ln1b = (const float*)d_in[2];
  const float* ln2g = (const float*)d_in[3];
  const float* ln2b = (const float*)d_in[4];
  const float* Wq   = (const float*)d_in[5];
  const float* bq   = (const float*)d_in[6];
  const float* Wk   = (const float*)d_in[7];
  const float* bk   = (const float*)d_in[8];
  const float* Wv   = (const float*)d_in[9];
  const float* bv   = (const float*)d_in[10];
  const float* Wp   = (const float*)d_in[11];
  const float* bp   = (const float*)d_in[12];
  const float* gW   = (const float*)d_in[13];
  const float* gb   = (const float*)d_in[14];
  const float* eW1  = (const float*)d_in[15];
  const float* eb1  = (const float*)d_in[16];
  const float* eW2  = (const float*)d_in[17];
  const float* eb2  = (const float*)d_in[18];
  float* out = (float*)d_out;
  (void)in_sizes; (void)n_in; (void)out_size;

  char* wsb = (char*)d_ws;
  size_t off = 0;
  auto alloc = [&](size_t bytes) -> void* {
    void* p = wsb + off;
    off += (bytes + 255) & ~(size_t)255;
    return p;
  };
  int*  counts  = (int*)alloc(32);
  int*  cursors = (int*)alloc(32);
  int*  off_al  = (int*)alloc(64);
  int*  ntiles  = (int*)alloc(64);
  int*  map_e   = (int*)alloc(MAX_TILES * 4);
  int*  map_row = (int*)alloc(MAX_TILES * 4);
  const size_t ctrl_bytes = off;
  int2*   tok_e   = (int2*)alloc((size_t)N_TOK * 8);
  float2* tok_w   = (float2*)alloc((size_t)N_TOK * 8);
  int2*   tok_pos = (int2*)alloc((size_t)N_TOK * 8);
  int*    list    = (int*)alloc((size_t)MAX_ROWS * 4);
  float* x1  = (float*)alloc((size_t)N_TOK * D_MODEL * 4);                       // 32 MB
  unsigned short* h2b = (unsigned short*)alloc((size_t)N_TOK * D_MODEL * 2);     // 16 MB
  unsigned short* W1T = (unsigned short*)alloc((size_t)NEXPERT * D_MODEL * H_MLP * 2);  // 64 MB
  unsigned short* W2T = (unsigned short*)alloc((size_t)NEXPERT * D_MODEL * H_MLP * 2);  // 64 MB
  float* ylist = (float*)alloc((size_t)MAX_ROWS * D_MODEL * 4);                  // 72 MB
  unsigned short* WqTh = (unsigned short*)alloc((size_t)D_MODEL * D_MODEL * 2);
  unsigned short* WqTl = (unsigned short*)alloc((size_t)D_MODEL * D_MODEL * 2);
  unsigned short* WkTh = (unsigned short*)alloc((size_t)D_MODEL * D_MODEL * 2);
  unsigned short* WkTl = (unsigned short*)alloc((size_t)D_MODEL * D_MODEL * 2);
  unsigned short* WvTh = (unsigned short*)alloc((size_t)D_MODEL * D_MODEL * 2);
  unsigned short* WvTl = (unsigned short*)alloc((size_t)D_MODEL * D_MODEL * 2);
  unsigned short* WpTh = (unsigned short*)alloc((size_t)D_MODEL * D_MODEL * 2);
  unsigned short* WpTl = (unsigned short*)alloc((size_t)D_MODEL * D_MODEL * 2);
  // Arena (160 MB): attention-phase f16 buffers alias MoE-phase `mid` (151 MB).
  char* arena = (char*)alloc((size_t)160 * MB);
  unsigned short* h1h = (unsigned short*)(arena);
  unsigned short* h1l = (unsigned short*)(arena + (size_t) 16 * MB);
  unsigned short* qh_ = (unsigned short*)(arena + (size_t) 32 * MB);
  unsigned short* ql_ = (unsigned short*)(arena + (size_t) 48 * MB);
  unsigned short* kh_ = (unsigned short*)(arena + (size_t) 64 * MB);
  unsigned short* kl_ = (unsigned short*)(arena + (size_t) 80 * MB);
  unsigned short* vh_ = (unsigned short*)(arena + (size_t) 96 * MB);
  unsigned short* vl_ = (unsigned short*)(arena + (size_t)112 * MB);
  unsigned short* vth_ = (unsigned short*)(arena + (size_t)128 * MB);
  unsigned short* vtl_ = (unsigned short*)(arena + (size_t)144 * MB);
  unsigned short* yh_ = vh_;   // reuse after vtrans
  unsigned short* yl_ = vl_;
  unsigned short* mid = (unsigned short*)(arena);  // 151 MB max, MoE phase
  if (off > ws_size) return;  // ws too small: output stays poisoned -> fails loudly

  hipMemsetAsync(d_ws, 0, ctrl_bytes, stream);

  transpose_cvt_kernel<<<dim3(H_MLP / 32, D_MODEL / 32, NEXPERT), dim3(32, 8), 0, stream>>>(
      eW1, W1T, D_MODEL, H_MLP);
  transpose_cvt_kernel<<<dim3(D_MODEL / 32, H_MLP / 32, NEXPERT), dim3(32, 8), 0, stream>>>(
      eW2, W2T, H_MLP, D_MODEL);
  transpose_cvt_f16_kernel<<<dim3(32, 32), dim3(32, 8), 0, stream>>>(Wq, WqTh, WqTl, D_MODEL, D_MODEL);
  transpose_cvt_f16_kernel<<<dim3(32, 32), dim3(32, 8), 0, stream>>>(Wk, WkTh, WkTl, D_MODEL, D_MODEL);
  transpose_cvt_f16_kernel<<<dim3(32, 32), dim3(32, 8), 0, stream>>>(Wv, WvTh, WvTl, D_MODEL, D_MODEL);
  transpose_cvt_f16_kernel<<<dim3(32, 32), dim3(32, 8), 0, stream>>>(Wp, WpTh, WpTl, D_MODEL, D_MODEL);

  ln1_kernel<<<N_TOK, 256, 0, stream>>>(x, ln1g, ln1b, h1h, h1l);

  gemm_split_kernel<0><<<dim3(8, 64), 256, 0, stream>>>(
      h1h, h1l, WqTh, WqTl, bq, nullptr, qh_, ql_, nullptr, N_TOK, D_MODEL, D_MODEL);
  gemm_split_kernel<0><<<dim3(8, 64), 256, 0, stream>>>(
      h1h, h1l, WkTh, WkTl, bk, nullptr, kh_, kl_, nullptr, N_TOK, D_MODEL, D_MODEL);
  gemm_split_kernel<0><<<dim3(8, 64), 256, 0, stream>>>(
      h1h, h1l, WvTh, WvTl, bv, nullptr, vh_, vl_, nullptr, N_TOK, D_MODEL, D_MODEL);

  vtrans_kernel<<<dim3(T_SEQ / 64, (N_TOK / T_SEQ) * NHEADS), 256, 0, stream>>>(vh_, vth_);
  vtrans_kernel<<<dim3(T_SEQ / 64, (N_TOK / T_SEQ) * NHEADS), 256, 0, stream>>>(vl_, vtl_);

  attn_mfma_kernel<<<dim3(T_SEQ / 128, (N_TOK / T_SEQ) * NHEADS), 512, 0, stream>>>(
      qh_, ql_, kh_, kl_, vth_, vtl_, yh_, yl_);

  gemm_split_kernel<1><<<dim3(8, 64), 256, 0, stream>>>(
      yh_, yl_, WpTh, WpTl, bp, x, nullptr, nullptr, x1, N_TOK, D_MODEL, D_MODEL);

  ln2_route_kernel<<<N_TOK, 256, 0, stream>>>(x1, ln2g, ln2b, gW, gb, h2b, tok_e, tok_w, counts);
  route_offsets_kernel<<<1, 64, 0, stream>>>(counts, off_al, ntiles, map_e, map_row);
  place_kernel<<<N_TOK / 256, 256, 0, stream>>>(tok_e, off_al, cursors, list, tok_pos);
  fill_pad_kernel<<<8, 256, 0, stream>>>(counts, off_al, list);

  moe_gemm_kernel<1, 1><<<dim3(H_MLP / 128, MAX_TILES), 256, 0, stream>>>(
      h2b, W1T, eb1, mid, nullptr, list, map_e, map_row, ntiles, D_MODEL, H_MLP);
  moe_gemm_kernel<0, 0><<<dim3(D_MODEL / 128, MAX_TILES), 256, 0, stream>>>(
      mid, W2T, eb2, nullptr, ylist, list, map_e, map_row, ntiles, H_MLP, D_MODEL);

  combine_kernel<<<N_TOK, 256, 0, stream>>>(x1, ylist, tok_pos, tok_w, out);
}

// Round 14
// 1309.012 us; speedup vs baseline: 1.3932x; 1.3932x over previous
//
#include <hip/hip_runtime.h>
#include <hip/hip_bf16.h>

#define D_MODEL 1024
#define H_MLP   4096
#define N_TOK   8192
#define T_SEQ   1024
#define NHEADS  16
#define HEAD_D  64
#define NEXPERT 8
#define LN_EPS  1e-5f
#define MAX_TILES 136
#define MAX_ROWS  (MAX_TILES * 128)
#define MB (1024 * 1024)

using f32x4 = __attribute__((ext_vector_type(4))) float;
using bh8   = __attribute__((ext_vector_type(8))) short;
typedef _Float16 h8 __attribute__((ext_vector_type(8)));

__device__ __forceinline__ unsigned short f2b(float f) {
  unsigned u = __float_as_uint(f);
  return (unsigned short)((u + 0x7FFFu + ((u >> 16) & 1u)) >> 16);
}
__device__ __forceinline__ float b2f(unsigned short h) {
  return __uint_as_float(((unsigned)h) << 16);
}
__device__ __forceinline__ void split16(float v, unsigned short& hi, unsigned short& lo) {
  const _Float16 h = (_Float16)v;
  const _Float16 l = (_Float16)(v - (float)h);
  hi = __builtin_bit_cast(unsigned short, h);
  lo = __builtin_bit_cast(unsigned short, l);
}
// global -> LDS async 16B copy. LDS dest: wave-uniform base + lane*16.
__device__ __forceinline__ void gll16(const unsigned short* g, unsigned short* lds) {
  __builtin_amdgcn_global_load_lds(
      (const __attribute__((address_space(1))) unsigned int*)(const void*)g,
      (__attribute__((address_space(3))) unsigned int*)(void*)lds, 16, 0, 0);
}

// ---------------- LayerNorm 1: f32 x -> f16 hi/lo h1 ----------------
__global__ __launch_bounds__(256) void ln1_kernel(
    const float* __restrict__ x, const float* __restrict__ g,
    const float* __restrict__ b, unsigned short* __restrict__ oh,
    unsigned short* __restrict__ ol) {
  const int t = blockIdx.x, tid = threadIdx.x;
  const float4 v = ((const float4*)(x + (size_t)t * D_MODEL))[tid];
  float s  = v.x + v.y + v.z + v.w;
  float sq = v.x * v.x + v.y * v.y + v.z * v.z + v.w * v.w;
  __shared__ float red[8];
  #pragma unroll
  for (int o = 32; o > 0; o >>= 1) { s += __shfl_down(s, o); sq += __shfl_down(sq, o); }
  if ((tid & 63) == 0) { red[tid >> 6] = s; red[4 + (tid >> 6)] = sq; }
  __syncthreads();
  s  = red[0] + red[1] + red[2] + red[3];
  sq = red[4] + red[5] + red[6] + red[7];
  const float mu = s * (1.0f / D_MODEL);
  const float var = sq * (1.0f / D_MODEL) - mu * mu;
  const float rs = 1.0f / sqrtf(var + LN_EPS);
  const float4 gv = ((const float4*)g)[tid];
  const float4 bv = ((const float4*)b)[tid];
  float4 o;
  o.x = (v.x - mu) * rs * gv.x + bv.x;
  o.y = (v.y - mu) * rs * gv.y + bv.y;
  o.z = (v.z - mu) * rs * gv.z + bv.z;
  o.w = (v.w - mu) * rs * gv.w + bv.w;
  ushort4 hs, ls;
  split16(o.x, hs.x, ls.x); split16(o.y, hs.y, ls.y);
  split16(o.z, hs.z, ls.z); split16(o.w, hs.w, ls.w);
  ((ushort4*)(oh + (size_t)t * D_MODEL))[tid] = hs;
  ((ushort4*)(ol + (size_t)t * D_MODEL))[tid] = ls;
}

// ------- split-f16 MFMA GEMM: C = A @ B^T + bias. A,B^T given as f16 hi/lo. -------
// Grid: x = column tile (fast, shares A-tile), y = row tile.
// MODE 0: C -> f16 hi/lo pair.  MODE 1: C -> f32 with +residual.
template<int MODE>
__global__ __launch_bounds__(256) void gemm_split_kernel(
    const unsigned short* __restrict__ Ah_g, const unsigned short* __restrict__ Al_g,
    const unsigned short* __restrict__ Bh_g, const unsigned short* __restrict__ Bl_g,
    const float* __restrict__ bias, const float* __restrict__ Rres,
    unsigned short* __restrict__ Ch, unsigned short* __restrict__ Cl,
    float* __restrict__ Cf, int M, int N, int K) {
  __shared__ unsigned short LAh[128 * 32], LAl[128 * 32];
  __shared__ unsigned short LBh[128 * 32], LBl[128 * 32];
  const int tid = threadIdx.x, lane = tid & 63, w = tid >> 6;
  const int bm = blockIdx.y * 128, bn = blockIdx.x * 128;
  const int wm = (w >> 1) * 64, wn = (w & 1) * 64;
  f32x4 acc[4][4];
  #pragma unroll
  for (int i = 0; i < 4; ++i)
    #pragma unroll
    for (int j = 0; j < 4; ++j) acc[i][j] = (f32x4){0.f, 0.f, 0.f, 0.f};
  const int lrow16 = lane >> 2, kq8 = (lane & 3) << 3;
  const int r0 = w * 16 + lrow16, r1 = 64 + w * 16 + lrow16;
  const size_t a0 = (size_t)(bm + r0) * K + kq8, a1 = (size_t)(bm + r1) * K + kq8;
  const size_t b0 = (size_t)(bn + r0) * K + kq8, b1 = (size_t)(bn + r1) * K + kq8;
  const int lb0 = (w * 16) * 32, lb1 = (64 + w * 16) * 32;
  const int lrow = lane & 15, lk = (lane >> 4) << 3;
  for (int k0 = 0; k0 < K; k0 += 32) {
    gll16(Ah_g + a0 + k0, &LAh[lb0]); gll16(Ah_g + a1 + k0, &LAh[lb1]);
    gll16(Al_g + a0 + k0, &LAl[lb0]); gll16(Al_g + a1 + k0, &LAl[lb1]);
    gll16(Bh_g + b0 + k0, &LBh[lb0]); gll16(Bh_g + b1 + k0, &LBh[lb1]);
    gll16(Bl_g + b0 + k0, &LBl[lb0]); gll16(Bl_g + b1 + k0, &LBl[lb1]);
    __syncthreads();
    h8 ah[4], al[4], bh[4], bl[4];
    #pragma unroll
    for (int i = 0; i < 4; ++i) {
      ah[i] = *(const h8*)&LAh[(wm + i * 16 + lrow) * 32 + lk];
      al[i] = *(const h8*)&LAl[(wm + i * 16 + lrow) * 32 + lk];
    }
    #pragma unroll
    for (int j = 0; j < 4; ++j) {
      bh[j] = *(const h8*)&LBh[(wn + j * 16 + lrow) * 32 + lk];
      bl[j] = *(const h8*)&LBl[(wn + j * 16 + lrow) * 32 + lk];
    }
    #pragma unroll
    for (int i = 0; i < 4; ++i)
      #pragma unroll
      for (int j = 0; j < 4; ++j) {
        acc[i][j] = __builtin_amdgcn_mfma_f32_16x16x32_f16(ah[i], bh[j], acc[i][j], 0, 0, 0);
        acc[i][j] = __builtin_amdgcn_mfma_f32_16x16x32_f16(ah[i], bl[j], acc[i][j], 0, 0, 0);
        acc[i][j] = __builtin_amdgcn_mfma_f32_16x16x32_f16(al[i], bh[j], acc[i][j], 0, 0, 0);
      }
    __syncthreads();
  }
  const int lc = lane & 15, lr4 = (lane >> 4) * 4;
  #pragma unroll
  for (int i = 0; i < 4; ++i)
    #pragma unroll
    for (int j = 0; j < 4; ++j) {
      const int col = bn + wn + j * 16 + lc;
      const float bsv = bias[col];
      #pragma unroll
      for (int qq = 0; qq < 4; ++qq) {
        const size_t row = (size_t)bm + wm + i * 16 + lr4 + qq;
        const size_t idx = row * N + col;
        const float v = acc[i][j][qq] + bsv;
        if (MODE == 0) {
          unsigned short hi, lo;
          split16(v, hi, lo);
          Ch[idx] = hi; Cl[idx] = lo;
        } else {
          Cf[idx] = v + Rres[idx];
        }
      }
    }
}

// ------- fused QKV split-f16 GEMM: one launch, 24 column tiles (8 per matrix) -------
__global__ __launch_bounds__(256) void gemm_qkv_kernel(
    const unsigned short* __restrict__ Ah_g, const unsigned short* __restrict__ Al_g,
    const unsigned short* __restrict__ BhQ, const unsigned short* __restrict__ BlQ,
    const unsigned short* __restrict__ BhK, const unsigned short* __restrict__ BlK,
    const unsigned short* __restrict__ BhV, const unsigned short* __restrict__ BlV,
    const float* __restrict__ bq, const float* __restrict__ bk, const float* __restrict__ bv,
    unsigned short* __restrict__ Qh, unsigned short* __restrict__ Ql,
    unsigned short* __restrict__ Kh_, unsigned short* __restrict__ Kl_,
    unsigned short* __restrict__ Vh_, unsigned short* __restrict__ Vl_,
    int M, int K) {
  __shared__ unsigned short LAh[128 * 32], LAl[128 * 32];
  __shared__ unsigned short LBh[128 * 32], LBl[128 * 32];
  const int tid = threadIdx.x, lane = tid & 63, w = tid >> 6;
  const int bm = blockIdx.y * 128;
  const int bng = blockIdx.x * 128;
  const int which = bng >> 10;          // block-uniform: 0=Q, 1=K, 2=V
  const int bn = bng & 1023;
  const unsigned short* Bh_g = (which == 0) ? BhQ : ((which == 1) ? BhK : BhV);
  const unsigned short* Bl_g = (which == 0) ? BlQ : ((which == 1) ? BlK : BlV);
  const float* bias = (which == 0) ? bq : ((which == 1) ? bk : bv);
  unsigned short* Ch = (which == 0) ? Qh : ((which == 1) ? Kh_ : Vh_);
  unsigned short* Cl = (which == 0) ? Ql : ((which == 1) ? Kl_ : Vl_);
  const int wm = (w >> 1) * 64, wn = (w & 1) * 64;
  f32x4 acc[4][4];
  #pragma unroll
  for (int i = 0; i < 4; ++i)
    #pragma unroll
    for (int j = 0; j < 4; ++j) acc[i][j] = (f32x4){0.f, 0.f, 0.f, 0.f};
  const int lrow16 = lane >> 2, kq8 = (lane & 3) << 3;
  const int r0 = w * 16 + lrow16, r1 = 64 + w * 16 + lrow16;
  const size_t a0 = (size_t)(bm + r0) * K + kq8, a1 = (size_t)(bm + r1) * K + kq8;
  const size_t b0 = (size_t)(bn + r0) * K + kq8, b1 = (size_t)(bn + r1) * K + kq8;
  const int lb0 = (w * 16) * 32, lb1 = (64 + w * 16) * 32;
  const int lrow = lane & 15, lk = (lane >> 4) << 3;
  for (int k0 = 0; k0 < K; k0 += 32) {
    gll16(Ah_g + a0 + k0, &LAh[lb0]); gll16(Ah_g + a1 + k0, &LAh[lb1]);
    gll16(Al_g + a0 + k0, &LAl[lb0]); gll16(Al_g + a1 + k0, &LAl[lb1]);
    gll16(Bh_g + b0 + k0, &LBh[lb0]); gll16(Bh_g + b1 + k0, &LBh[lb1]);
    gll16(Bl_g + b0 + k0, &LBl[lb0]); gll16(Bl_g + b1 + k0, &LBl[lb1]);
    __syncthreads();
    h8 ah[4], al[4], bh[4], bl[4];
    #pragma unroll
    for (int i = 0; i < 4; ++i) {
      ah[i] = *(const h8*)&LAh[(wm + i * 16 + lrow) * 32 + lk];
      al[i] = *(const h8*)&LAl[(wm + i * 16 + lrow) * 32 + lk];
    }
    #pragma unroll
    for (int j = 0; j < 4; ++j) {
      bh[j] = *(const h8*)&LBh[(wn + j * 16 + lrow) * 32 + lk];
      bl[j] = *(const h8*)&LBl[(wn + j * 16 + lrow) * 32 + lk];
    }
    #pragma unroll
    for (int i = 0; i < 4; ++i)
      #pragma unroll
      for (int j = 0; j < 4; ++j) {
        acc[i][j] = __builtin_amdgcn_mfma_f32_16x16x32_f16(ah[i], bh[j], acc[i][j], 0, 0, 0);
        acc[i][j] = __builtin_amdgcn_mfma_f32_16x16x32_f16(ah[i], bl[j], acc[i][j], 0, 0, 0);
        acc[i][j] = __builtin_amdgcn_mfma_f32_16x16x32_f16(al[i], bh[j], acc[i][j], 0, 0, 0);
      }
    __syncthreads();
  }
  const int lc = lane & 15, lr4 = (lane >> 4) * 4;
  #pragma unroll
  for (int i = 0; i < 4; ++i)
    #pragma unroll
    for (int j = 0; j < 4; ++j) {
      const int col = bn + wn + j * 16 + lc;
      const float bsv = bias[col];
      #pragma unroll
      for (int qq = 0; qq < 4; ++qq) {
        const size_t row = (size_t)bm + wm + i * 16 + lr4 + qq;
        const size_t idx = row * D_MODEL + col;
        const float v = acc[i][j][qq] + bsv;
        unsigned short hi, lo;
        split16(v, hi, lo);
        Ch[idx] = hi; Cl[idx] = lo;
      }
    }
}

// ------------- V transpose (hi+lo fused): [B,T,H*64] f16 -> [B*H, 64, T] f16 -------------
__global__ __launch_bounds__(256) void vtrans_kernel(
    const unsigned short* __restrict__ srch, unsigned short* __restrict__ dsth,
    const unsigned short* __restrict__ srcl, unsigned short* __restrict__ dstl) {
  __shared__ unsigned short tile[64][72];
  const int tid = threadIdx.x;
  const int t0 = blockIdx.x * 64, bh = blockIdx.y;
  const int b = bh >> 4, h = bh & 15;
  const unsigned short* src = blockIdx.z ? srcl : srch;
  unsigned short* dst = blockIdx.z ? dstl : dsth;
  #pragma unroll
  for (int it = 0; it < 2; ++it) {
    const int sg = tid + it * 256;
    const int r = sg >> 3, s = sg & 7;
    *(uint4*)&tile[r][s * 8] =
        *(const uint4*)(src + ((size_t)b * T_SEQ + t0 + r) * D_MODEL + h * HEAD_D + s * 8);
  }
  __syncthreads();
  #pragma unroll
  for (int it = 0; it < 2; ++it) {
    const int sg = tid + it * 256;
    const int d = sg >> 3, s = sg & 7;
    unsigned short v8[8] __attribute__((aligned(16)));
    #pragma unroll
    for (int j = 0; j < 8; ++j) v8[j] = tile[s * 8 + j][d];
    *(uint4*)(dst + ((size_t)bh * HEAD_D + d) * T_SEQ + t0 + s * 8) = *(const uint4*)v8;
  }
}

// ---- causal flash attention v2: 8 waves, QB=128, KB=64, split-f16 MFMA ----
__global__ __launch_bounds__(512) void attn_mfma_kernel(
    const unsigned short* __restrict__ qh_g, const unsigned short* __restrict__ ql_g,
    const unsigned short* __restrict__ kh_g, const unsigned short* __restrict__ kl_g,
    const unsigned short* __restrict__ vth_g, const unsigned short* __restrict__ vtl_g,
    unsigned short* __restrict__ yh, unsigned short* __restrict__ yl) {
  __shared__ unsigned short Kh[64][72], Kl[64][72], Vh[64][72], Vl[64][72];
  __shared__ float Ps[8][16][36];   // per-wave P scratch, one 32-k half at a time
  const int tid = threadIdx.x, lane = tid & 63, w = tid >> 6;       // w = 0..7
  const int g = lane >> 4, c = lane & 15;
  const int qt = (int)gridDim.x - 1 - (int)blockIdx.x;              // big tiles first
  const int bh = blockIdx.y, b = bh >> 4, h = bh & 15;
  const size_t qrow0 = (size_t)b * T_SEQ + qt * 128;
  h8 aqh[2], aql[2];
  {
    const size_t rq = (qrow0 + w * 16 + c) * D_MODEL + h * HEAD_D + g * 8;
    aqh[0] = *(const h8*)(qh_g + rq);
    aqh[1] = *(const h8*)(qh_g + rq + 32);
    aql[0] = *(const h8*)(ql_g + rq);
    aql[1] = *(const h8*)(ql_g + rq + 32);
  }
  f32x4 oacc[4];
  #pragma unroll
  for (int i = 0; i < 4; ++i) oacc[i] = (f32x4){0.f, 0.f, 0.f, 0.f};
  float m[4] = {-3e38f, -3e38f, -3e38f, -3e38f};
  float l[4] = {0.f, 0.f, 0.f, 0.f};
  const int sgr = tid >> 3, sgs = tid & 7;   // 512 threads: one uint4 per buffer each
  const int nkt = 2 * qt + 2;
  for (int kt = 0; kt < nkt; ++kt) {
    const int kv0 = kt * 64;
    __syncthreads();
    {
      const size_t kb = ((size_t)b * T_SEQ + kv0 + sgr) * D_MODEL + h * HEAD_D + sgs * 8;
      const size_t vb = ((size_t)bh * HEAD_D + sgr) * T_SEQ + kv0 + sgs * 8;
      *(uint4*)&Kh[sgr][sgs * 8] = *(const uint4*)(kh_g + kb);
      *(uint4*)&Kl[sgr][sgs * 8] = *(const uint4*)(kl_g + kb);
      *(uint4*)&Vh[sgr][sgs * 8] = *(const uint4*)(vth_g + vb);
      *(uint4*)&Vl[sgr][sgs * 8] = *(const uint4*)(vtl_g + vb);
    }
    __syncthreads();
    f32x4 sv[4];
    __builtin_amdgcn_s_setprio(1);
    #pragma unroll
    for (int nt = 0; nt < 4; ++nt) {
      f32x4 s = {0.f, 0.f, 0.f, 0.f};
      #pragma unroll
      for (int ks = 0; ks < 2; ++ks) {
        const h8 bkh = *(const h8*)&Kh[nt * 16 + c][ks * 32 + g * 8];
        const h8 bkl = *(const h8*)&Kl[nt * 16 + c][ks * 32 + g * 8];
        s = __builtin_amdgcn_mfma_f32_16x16x32_f16(aqh[ks], bkh, s, 0, 0, 0);
        s = __builtin_amdgcn_mfma_f32_16x16x32_f16(aqh[ks], bkl, s, 0, 0, 0);
        s = __builtin_amdgcn_mfma_f32_16x16x32_f16(aql[ks], bkh, s, 0, 0, 0);
      }
      sv[nt] = s;
    }
    __builtin_amdgcn_s_setprio(0);
    float pm[4] = {-3e38f, -3e38f, -3e38f, -3e38f};
    #pragma unroll
    for (int nt = 0; nt < 4; ++nt)
      #pragma unroll
      for (int qq = 0; qq < 4; ++qq) {
        float sval = sv[nt][qq] * 0.125f;
        const int krow = kv0 + nt * 16 + c;
        const int qrow = qt * 128 + w * 16 + g * 4 + qq;
        sval = (krow <= qrow) ? sval : -3.0e38f;
        sv[nt][qq] = sval;
        pm[qq] = fmaxf(pm[qq], sval);
      }
    #pragma unroll
    for (int o = 1; o < 16; o <<= 1)
      #pragma unroll
      for (int qq = 0; qq < 4; ++qq) pm[qq] = fmaxf(pm[qq], __shfl_xor(pm[qq], o));
    float psum[4];
    #pragma unroll
    for (int qq = 0; qq < 4; ++qq) {
      const float mnew = fmaxf(m[qq], pm[qq]);
      const float sc = expf(m[qq] - mnew);
      m[qq] = mnew;
      l[qq] *= sc;
      #pragma unroll
      for (int dt = 0; dt < 4; ++dt) oacc[dt][qq] *= sc;
      psum[qq] = 0.f;
    }
    #pragma unroll
    for (int nt = 0; nt < 4; ++nt)
      #pragma unroll
      for (int qq = 0; qq < 4; ++qq) {
        const float p = expf(sv[nt][qq] - m[qq]);
        sv[nt][qq] = p;
        psum[qq] += p;
      }
    #pragma unroll
    for (int o = 1; o < 16; o <<= 1)
      #pragma unroll
      for (int qq = 0; qq < 4; ++qq) psum[qq] += __shfl_xor(psum[qq], o);
    #pragma unroll
    for (int qq = 0; qq < 4; ++qq) l[qq] += psum[qq];
    #pragma unroll
    for (int half = 0; half < 2; ++half) {
      #pragma unroll
      for (int nt2 = 0; nt2 < 2; ++nt2)
        #pragma unroll
        for (int qq = 0; qq < 4; ++qq)
          Ps[w][g * 4 + qq][nt2 * 16 + c] = sv[half * 2 + nt2][qq];
      const float4 p0 = *(const float4*)&Ps[w][c][g * 8];
      const float4 p1 = *(const float4*)&Ps[w][c][g * 8 + 4];
      const float pv[8] = {p0.x, p0.y, p0.z, p0.w, p1.x, p1.y, p1.z, p1.w};
      h8 pah, pal;
      #pragma unroll
      for (int j = 0; j < 8; ++j) {
        const _Float16 hi = (_Float16)pv[j];
        pah[j] = hi;
        pal[j] = (_Float16)(pv[j] - (float)hi);
      }
      __builtin_amdgcn_s_setprio(1);
      #pragma unroll
      for (int dt = 0; dt < 4; ++dt) {
        const h8 bvh = *(const h8*)&Vh[dt * 16 + c][half * 32 + g * 8];
        const h8 bvl = *(const h8*)&Vl[dt * 16 + c][half * 32 + g * 8];
        oacc[dt] = __builtin_amdgcn_mfma_f32_16x16x32_f16(pah, bvh, oacc[dt], 0, 0, 0);
        oacc[dt] = __builtin_amdgcn_mfma_f32_16x16x32_f16(pah, bvl, oacc[dt], 0, 0, 0);
        oacc[dt] = __builtin_amdgcn_mfma_f32_16x16x32_f16(pal, bvh, oacc[dt], 0, 0, 0);
      }
      __builtin_amdgcn_s_setprio(0);
      if (half == 0) __builtin_amdgcn_sched_barrier(0);
    }
  }
  #pragma unroll
  for (int qq = 0; qq < 4; ++qq) {
    const float inv = 1.0f / l[qq];
    const size_t row = (qrow0 + w * 16 + g * 4 + qq) * D_MODEL + h * HEAD_D;
    #pragma unroll
    for (int dt = 0; dt < 4; ++dt) {
      unsigned short hi, lo;
      split16(oacc[dt][qq] * inv, hi, lo);
      yh[row + dt * 16 + c] = hi;
      yl[row + dt * 16 + c] = lo;
    }
  }
}

// ------------- LN2 + gate logits + top2 routing (f32) -------------
__global__ __launch_bounds__(256) void ln2_route_kernel(
    const float* __restrict__ x1, const float* __restrict__ g,
    const float* __restrict__ b, const float* __restrict__ gW,
    const float* __restrict__ gb, unsigned short* __restrict__ h2b,
    int2* __restrict__ tok_e, float2* __restrict__ tok_w, int* __restrict__ counts) {
  const int t = blockIdx.x, tid = threadIdx.x;
  const float4 v = ((const float4*)(x1 + (size_t)t * D_MODEL))[tid];
  float s  = v.x + v.y + v.z + v.w;
  float sq = v.x * v.x + v.y * v.y + v.z * v.z + v.w * v.w;
  __shared__ float red[8];
  __shared__ float lred[4][8];
  #pragma unroll
  for (int o = 32; o > 0; o >>= 1) { s += __shfl_down(s, o); sq += __shfl_down(sq, o); }
  if ((tid & 63) == 0) { red[tid >> 6] = s; red[4 + (tid >> 6)] = sq; }
  __syncthreads();
  s  = red[0] + red[1] + red[2] + red[3];
  sq = red[4] + red[5] + red[6] + red[7];
  const float mu = s * (1.0f / D_MODEL);
  const float var = sq * (1.0f / D_MODEL) - mu * mu;
  const float rs = 1.0f / sqrtf(var + LN_EPS);
  const float4 gv = ((const float4*)g)[tid];
  const float4 bv = ((const float4*)b)[tid];
  float4 hv;
  hv.x = (v.x - mu) * rs * gv.x + bv.x;
  hv.y = (v.y - mu) * rs * gv.y + bv.y;
  hv.z = (v.z - mu) * rs * gv.z + bv.z;
  hv.w = (v.w - mu) * rs * gv.w + bv.w;
  ushort4 hs;
  hs.x = f2b(hv.x); hs.y = f2b(hv.y); hs.z = f2b(hv.z); hs.w = f2b(hv.w);
  ((ushort4*)(h2b + (size_t)t * D_MODEL))[tid] = hs;
  float lg[8];
  const float* gwr = gW + (size_t)tid * 32;
  #pragma unroll
  for (int e = 0; e < 8; ++e)
    lg[e] = hv.x * gwr[e] + hv.y * gwr[8 + e] +
            hv.z * gwr[16 + e] + hv.w * gwr[24 + e];
  #pragma unroll
  for (int o = 32; o > 0; o >>= 1)
    #pragma unroll
    for (int e = 0; e < 8; ++e) lg[e] += __shfl_down(lg[e], o);
  if ((tid & 63) == 0)
    #pragma unroll
    for (int e = 0; e < 8; ++e) lred[tid >> 6][e] = lg[e];
  __syncthreads();
  if (tid == 0) {
    float L[8];
    #pragma unroll
    for (int e = 0; e < 8; ++e)
      L[e] = lred[0][e] + lred[1][e] + lred[2][e] + lred[3][e] + gb[e];
    int e0 = 0; float v0 = L[0];
    for (int e = 1; e < 8; ++e) if (L[e] > v0) { v0 = L[e]; e0 = e; }
    int e1 = (e0 == 0) ? 1 : 0; float v1 = L[e1];
    for (int e = 0; e < 8; ++e) if (e != e0 && L[e] > v1) { v1 = L[e]; e1 = e; }
    const float ew = expf(v1 - v0);
    const float inv = 1.0f / (1.0f + ew);
    tok_e[t] = make_int2(e0, e1);
    tok_w[t] = make_float2(inv, ew * inv);
    atomicAdd(&counts[e0], 1);
    atomicAdd(&counts[e1], 1);
  }
}

// ------------- routing bookkeeping (128-aligned expert segments) -------------
__global__ void route_offsets_kernel(const int* __restrict__ counts, int* __restrict__ off_al,
    int* __restrict__ ntiles, int* __restrict__ map_e, int* __restrict__ map_row) {
  if (threadIdx.x != 0 || blockIdx.x != 0) return;
  int off = 0, ti = 0;
  for (int e = 0; e < NEXPERT; ++e) {
    off_al[e] = off;
    const int tiles = (counts[e] + 127) >> 7;
    for (int j = 0; j < tiles; ++j) { map_e[ti] = e; map_row[ti] = off + (j << 7); ++ti; }
    off += tiles << 7;
  }
  off_al[NEXPERT] = off;
  ntiles[0] = ti;
}

__global__ __launch_bounds__(256) void place_kernel(
    const int2* __restrict__ tok_e, const int* __restrict__ off_al,
    int* __restrict__ cursors, int* __restrict__ list, int2* __restrict__ tok_pos) {
  const int t = blockIdx.x * 256 + threadIdx.x;
  if (t >= N_TOK) return;
  const int2 te = tok_e[t];
  const int p0 = off_al[te.x] + atomicAdd(&cursors[te.x], 1);
  const int p1 = off_al[te.y] + atomicAdd(&cursors[te.y], 1);
  list[p0] = t; list[p1] = t;
  tok_pos[t] = make_int2(p0, p1);
}

__global__ __launch_bounds__(256) void fill_pad_kernel(
    const int* __restrict__ counts, const int* __restrict__ off_al, int* __restrict__ list) {
  const int i = blockIdx.x * 256 + threadIdx.x;
  const int e = i >> 7, j = i & 127;
  if (e >= NEXPERT) return;
  const int start = off_al[e] + counts[e];
  if (start + j < off_al[e + 1]) list[start + j] = 0;
}

// ------------- f32 -> bf16 transpose (expert weights -> [N][K] layout) -------------
__global__ void transpose_cvt_kernel(
    const float* __restrict__ in, unsigned short* __restrict__ outp, int R, int C) {
  __shared__ float tile[32][33];
  const int e = blockIdx.z;
  const float* I = in + (size_t)e * R * C;
  unsigned short* O = outp + (size_t)e * R * C;
  const int c0 = blockIdx.x * 32, r0 = blockIdx.y * 32;
  const int tx = threadIdx.x, ty = threadIdx.y;
  #pragma unroll
  for (int j = 0; j < 32; j += 8)
    tile[ty + j][tx] = I[(size_t)(r0 + ty + j) * C + c0 + tx];
  __syncthreads();
  #pragma unroll
  for (int j = 0; j < 32; j += 8)
    O[(size_t)(c0 + ty + j) * R + r0 + tx] = f2b(tile[tx][ty + j]);
}

// ------------- f32 -> f16 hi/lo transpose (proj weights -> [N][K]) -------------
__global__ void transpose_cvt_f16_kernel(
    const float* __restrict__ in, unsigned short* __restrict__ oh,
    unsigned short* __restrict__ ol, int R, int C) {
  __shared__ float tile[32][33];
  const int c0 = blockIdx.x * 32, r0 = blockIdx.y * 32;
  const int tx = threadIdx.x, ty = threadIdx.y;
  #pragma unroll
  for (int j = 0; j < 32; j += 8)
    tile[ty + j][tx] = in[(size_t)(r0 + ty + j) * C + c0 + tx];
  __syncthreads();
  #pragma unroll
  for (int j = 0; j < 32; j += 8) {
    unsigned short hi, lo;
    split16(tile[tx][ty + j], hi, lo);
    oh[(size_t)(c0 + ty + j) * R + r0 + tx] = hi;
    ol[(size_t)(c0 + ty + j) * R + r0 + tx] = lo;
  }
}

// ------------- expert GEMM: bf16 MFMA 16x16x32, 128x128 tile, gll staging -------------
// Grid: x = column tile (fast, shares A-tile), y = M-tile (mt).  (round-9 form)
template<int GELU_OUT, int GATHER>
__global__ __launch_bounds__(256) void moe_gemm_kernel(
    const unsigned short* __restrict__ Abase, const unsigned short* __restrict__ Bbase,
    const float* __restrict__ biasBase, unsigned short* __restrict__ midOut,
    float* __restrict__ fOut, const int* __restrict__ list,
    const int* __restrict__ map_e, const int* __restrict__ map_row,
    const int* __restrict__ ntiles_p, int K, int N) {
  const int mt = blockIdx.y;
  if (mt >= ntiles_p[0]) return;
  const int e = map_e[mt];
  const int row0 = map_row[mt];
  const int bn = blockIdx.x * 128;
  const unsigned short* Bp = Bbase + (size_t)e * (size_t)N * (size_t)K;
  const float* bias = biasBase + (size_t)e * N;
  __shared__ unsigned short As[128 * 32];
  __shared__ unsigned short Bs[128 * 32];
  const int tid = threadIdx.x, lane = tid & 63, wid = tid >> 6;
  const int wm = (wid >> 1) * 64, wn = (wid & 1) * 64;
  f32x4 acc[4][4];
  #pragma unroll
  for (int i = 0; i < 4; ++i)
    #pragma unroll
    for (int j = 0; j < 4; ++j) acc[i][j] = (f32x4){0.f, 0.f, 0.f, 0.f};
  const int lrow16 = lane >> 2, kq8 = (lane & 3) << 3;
  const int r0 = wid * 16 + lrow16, r1 = 64 + wid * 16 + lrow16;
  size_t arow0, arow1;
  if (GATHER) {
    arow0 = (size_t)list[row0 + r0] * (size_t)K + kq8;
    arow1 = (size_t)list[row0 + r1] * (size_t)K + kq8;
  } else {
    arow0 = (size_t)(row0 + r0) * (size_t)K + kq8;
    arow1 = (size_t)(row0 + r1) * (size_t)K + kq8;
  }
  const size_t brow0 = (size_t)(bn + r0) * (size_t)K + kq8;
  const size_t brow1 = (size_t)(bn + r1) * (size_t)K + kq8;
  const int lb0 = (wid * 16) * 32, lb1 = (64 + wid * 16) * 32;
  const int lrow = lane & 15, lk = (lane >> 4) << 3;
  for (int k0 = 0; k0 < K; k0 += 32) {
    gll16(Abase + arow0 + k0, &As[lb0]);
    gll16(Abase + arow1 + k0, &As[lb1]);
    gll16(Bp + brow0 + k0, &Bs[lb0]);
    gll16(Bp + brow1 + k0, &Bs[lb1]);
    __syncthreads();
    bh8 a[4], b[4];
    #pragma unroll
    for (int i = 0; i < 4; ++i) a[i] = *(const bh8*)&As[(wm + i * 16 + lrow) * 32 + lk];
    #pragma unroll
    for (int j = 0; j < 4; ++j) b[j] = *(const bh8*)&Bs[(wn + j * 16 + lrow) * 32 + lk];
    #pragma unroll
    for (int i = 0; i < 4; ++i)
      #pragma unroll
      for (int j = 0; j < 4; ++j)
        acc[i][j] = __builtin_amdgcn_mfma_f32_16x16x32_bf16(a[i], b[j], acc[i][j], 0, 0, 0);
    __syncthreads();
  }
  const int lc = lane & 15, lr4 = (lane >> 4) * 4;
  #pragma unroll
  for (int i = 0; i < 4; ++i)
    #pragma unroll
    for (int j = 0; j < 4; ++j) {
      const int col = bn + wn + j * 16 + lc;
      const float bsv = bias[col];
      #pragma unroll
      for (int qq = 0; qq < 4; ++qq) {
        const int rowl = wm + i * 16 + lr4 + qq;
        const size_t idx = (size_t)(row0 + rowl) * N + col;
        const float xv = acc[i][j][qq] + bsv;
        if (GELU_OUT) {
          const float gel = 0.5f * xv * (1.0f + erff(xv * 0.70710678118654752f));
          midOut[idx] = f2b(gel);
        } else {
          fOut[idx] = xv;
        }
      }
    }
}

// ------------- combine: out = x1 + w0*y[pos0] + w1*y[pos1], f32 out -------------
__global__ __launch_bounds__(256) void combine_kernel(
    const float* __restrict__ x1, const float* __restrict__ ylist,
    const int2* __restrict__ tok_pos, const float2* __restrict__ tok_w,
    float* __restrict__ outp) {
  const int t = blockIdx.x, tid = threadIdx.x;
  const int2 p = tok_pos[t];
  const float2 w = tok_w[t];
  const float4 a  = ((const float4*)(x1 + (size_t)t * D_MODEL))[tid];
  const float4 y0 = ((const float4*)(ylist + (size_t)p.x * D_MODEL))[tid];
  const float4 y1 = ((const float4*)(ylist + (size_t)p.y * D_MODEL))[tid];
  float4 o;
  o.x = a.x + w.x * y0.x + w.y * y1.x;
  o.y = a.y + w.x * y0.y + w.y * y1.y;
  o.z = a.z + w.x * y0.z + w.y * y1.z;
  o.w = a.w + w.x * y0.w + w.y * y1.w;
  ((float4*)(outp + (size_t)t * D_MODEL))[tid] = o;
}

extern "C" void kernel_launch(void* const* d_in, const int* in_sizes, int n_in,
                              void* d_out, int out_size, void* d_ws, size_t ws_size,
                              hipStream_t stream) {
  const float* x    = (const float*)d_in[0];
  const float* ln1g = (const float*)d_in[1];
  const float* ln1b = (const float*)d_in[2];
  const float* ln2g = (const float*)d_in[3];
  const float* ln2b = (const float*)d_in[4];
  const float* Wq   = (const float*)d_in[5];
  const float* bq   = (const float*)d_in[6];
  const float* Wk   = (const float*)d_in[7];
  const float* bk   = (const float*)d_in[8];
  const float* Wv   = (const float*)d_in[9];
  const float* bv   = (const float*)d_in[10];
  const float* Wp   = (const float*)d_in[11];
  const float* bp   = (const float*)d_in[12];
  const float* gW   = (const float*)d_in[13];
  const float* gb   = (const float*)d_in[14];
  const float* eW1  = (const float*)d_in[15];
  const float* eb1  = (const float*)d_in[16];
  const float* eW2  = (const float*)d_in[17];
  const float* eb2  = (const float*)d_in[18];
  float* out = (float*)d_out;
  (void)in_sizes; (void)n_in; (void)out_size;

  char* wsb = (char*)d_ws;
  size_t off = 0;
  auto alloc = [&](size_t bytes) -> void* {
    void* p = wsb + off;
    off += (bytes + 255) & ~(size_t)255;
    return p;
  };
  int*  counts  = (int*)alloc(32);
  int*  cursors = (int*)alloc(32);
  int*  off_al  = (int*)alloc(64);
  int*  ntiles  = (int*)alloc(64);
  int*  map_e   = (int*)alloc(MAX_TILES * 4);
  int*  map_row = (int*)alloc(MAX_TILES * 4);
  const size_t ctrl_bytes = off;
  int2*   tok_e   = (int2*)alloc((size_t)N_TOK * 8);
  float2* tok_w   = (float2*)alloc((size_t)N_TOK * 8);
  int2*   tok_pos = (int2*)alloc((size_t)N_TOK * 8);
  int*    list    = (int*)alloc((size_t)MAX_ROWS * 4);
  float* x1  = (float*)alloc((size_t)N_TOK * D_MODEL * 4);                       // 32 MB
  unsigned short* h2b = (unsigned short*)alloc((size_t)N_TOK * D_MODEL * 2);     // 16 MB
  unsigned short* W1T = (unsigned short*)alloc((size_t)NEXPERT * D_MODEL * H_MLP * 2);  // 64 MB
  unsigned short* W2T = (unsigned short*)alloc((size_t)NEXPERT * D_MODEL * H_MLP * 2);  // 64 MB
  float* ylist = (float*)alloc((size_t)MAX_ROWS * D_MODEL * 4);                  // 68 MB
  unsigned short* WqTh = (unsigned short*)alloc((size_t)D_MODEL * D_MODEL * 2);
  unsigned short* WqTl = (unsigned short*)alloc((size_t)D_MODEL * D_MODEL * 2);
  unsigned short* WkTh = (unsigned short*)alloc((size_t)D_MODEL * D_MODEL * 2);
  unsigned short* WkTl = (unsigned short*)alloc((size_t)D_MODEL * D_MODEL * 2);
  unsigned short* WvTh = (unsigned short*)alloc((size_t)D_MODEL * D_MODEL * 2);
  unsigned short* WvTl = (unsigned short*)alloc((size_t)D_MODEL * D_MODEL * 2);
  unsigned short* WpTh = (unsigned short*)alloc((size_t)D_MODEL * D_MODEL * 2);
  unsigned short* WpTl = (unsigned short*)alloc((size_t)D_MODEL * D_MODEL * 2);
  // Arena (160 MB): attention-phase f16 buffers alias MoE-phase `mid` (136 MB).
  char* arena = (char*)alloc((size_t)160 * MB);
  unsigned short* h1h = (unsigned short*)(arena);
  unsigned short* h1l = (unsigned short*)(arena + (size_t) 16 * MB);
  unsigned short* qh_ = (unsigned short*)(arena + (size_t) 32 * MB);
  unsigned short* ql_ = (unsigned short*)(arena + (size_t) 48 * MB);
  unsigned short* kh_ = (unsigned short*)(arena + (size_t) 64 * MB);
  unsigned short* kl_ = (unsigned short*)(arena + (size_t) 80 * MB);
  unsigned short* vh_ = (unsigned short*)(arena + (size_t) 96 * MB);
  unsigned short* vl_ = (unsigned short*)(arena + (size_t)112 * MB);
  unsigned short* vth_ = (unsigned short*)(arena + (size_t)128 * MB);
  unsigned short* vtl_ = (unsigned short*)(arena + (size_t)144 * MB);
  unsigned short* yh_ = vh_;   // reuse after vtrans
  unsigned short* yl_ = vl_;
  unsigned short* mid = (unsigned short*)(arena);  // 136 MB, MoE phase
  if (off > ws_size) return;  // ws too small: output stays poisoned -> fails loudly

  hipMemsetAsync(d_ws, 0, ctrl_bytes, stream);

  transpose_cvt_kernel<<<dim3(H_MLP / 32, D_MODEL / 32, NEXPERT), dim3(32, 8), 0, stream>>>(
      eW1, W1T, D_MODEL, H_MLP);
  transpose_cvt_kernel<<<dim3(D_MODEL / 32, H_MLP / 32, NEXPERT), dim3(32, 8), 0, stream>>>(
      eW2, W2T, H_MLP, D_MODEL);
  transpose_cvt_f16_kernel<<<dim3(32, 32), dim3(32, 8), 0, stream>>>(Wq, WqTh, WqTl, D_MODEL, D_MODEL);
  transpose_cvt_f16_kernel<<<dim3(32, 32), dim3(32, 8), 0, stream>>>(Wk, WkTh, WkTl, D_MODEL, D_MODEL);
  transpose_cvt_f16_kernel<<<dim3(32, 32), dim3(32, 8), 0, stream>>>(Wv, WvTh, WvTl, D_MODEL, D_MODEL);
  transpose_cvt_f16_kernel<<<dim3(32, 32), dim3(32, 8), 0, stream>>>(Wp, WpTh, WpTl, D_MODEL, D_MODEL);

  ln1_kernel<<<N_TOK, 256, 0, stream>>>(x, ln1g, ln1b, h1h, h1l);

  gemm_qkv_kernel<<<dim3(24, 64), 256, 0, stream>>>(
      h1h, h1l, WqTh, WqTl, WkTh, WkTl, WvTh, WvTl, bq, bk, bv,
      qh_, ql_, kh_, kl_, vh_, vl_, N_TOK, D_MODEL);

  vtrans_kernel<<<dim3(T_SEQ / 64, (N_TOK / T_SEQ) * NHEADS, 2), 256, 0, stream>>>(
      vh_, vth_, vl_, vtl_);

  attn_mfma_kernel<<<dim3(T_SEQ / 128, (N_TOK / T_SEQ) * NHEADS), 512, 0, stream>>>(
      qh_, ql_, kh_, kl_, vth_, vtl_, yh_, yl_);

  gemm_split_kernel<1><<<dim3(8, 64), 256, 0, stream>>>(
      yh_, yl_, WpTh, WpTl, bp, x, nullptr, nullptr, x1, N_TOK, D_MODEL, D_MODEL);

  ln2_route_kernel<<<N_TOK, 256, 0, stream>>>(x1, ln2g, ln2b, gW, gb, h2b, tok_e, tok_w, counts);
  route_offsets_kernel<<<1, 64, 0, stream>>>(counts, off_al, ntiles, map_e, map_row);
  place_kernel<<<N_TOK / 256, 256, 0, stream>>>(tok_e, off_al, cursors, list, tok_pos);
  fill_pad_kernel<<<4, 256, 0, stream>>>(counts, off_al, list);

  moe_gemm_kernel<1, 1><<<dim3(H_MLP / 128, MAX_TILES), 256, 0, stream>>>(
      h2b, W1T, eb1, mid, nullptr, list, map_e, map_row, ntiles, D_MODEL, H_MLP);
  moe_gemm_kernel<0, 0><<<dim3(D_MODEL / 128, MAX_TILES), 256, 0, stream>>>(
      mid, W2T, eb2, nullptr, ylist, list, map_e, map_row, ntiles, H_MLP, D_MODEL);

  combine_kernel<<<N_TOK, 256, 0, stream>>>(x1, ylist, tok_pos, tok_w, out);
}

// Round 15
// 1255.574 us; speedup vs baseline: 1.4525x; 1.0426x over previous
//
#include <hip/hip_runtime.h>
#include <hip/hip_bf16.h>

#define D_MODEL 1024
#define H_MLP   4096
#define N_TOK   8192
#define T_SEQ   1024
#define NHEADS  16
#define HEAD_D  64
#define NEXPERT 8
#define LN_EPS  1e-5f
#define MAX_TILES 136
#define MAX_ROWS  (MAX_TILES * 128)
#define MB (1024 * 1024)

using f32x4 = __attribute__((ext_vector_type(4))) float;
using bh8   = __attribute__((ext_vector_type(8))) short;
typedef _Float16 h8 __attribute__((ext_vector_type(8)));

__device__ __forceinline__ unsigned short f2b(float f) {
  unsigned u = __float_as_uint(f);
  return (unsigned short)((u + 0x7FFFu + ((u >> 16) & 1u)) >> 16);
}
__device__ __forceinline__ float b2f(unsigned short h) {
  return __uint_as_float(((unsigned)h) << 16);
}
__device__ __forceinline__ void split16(float v, unsigned short& hi, unsigned short& lo) {
  const _Float16 h = (_Float16)v;
  const _Float16 l = (_Float16)(v - (float)h);
  hi = __builtin_bit_cast(unsigned short, h);
  lo = __builtin_bit_cast(unsigned short, l);
}
// global -> LDS async 16B copy. LDS dest: wave-uniform base + lane*16.
__device__ __forceinline__ void gll16(const unsigned short* g, unsigned short* lds) {
  __builtin_amdgcn_global_load_lds(
      (const __attribute__((address_space(1))) unsigned int*)(const void*)g,
      (__attribute__((address_space(3))) unsigned int*)(void*)lds, 16, 0, 0);
}

// ---------------- LayerNorm 1: f32 x -> f16 hi/lo h1 ----------------
__global__ __launch_bounds__(256) void ln1_kernel(
    const float* __restrict__ x, const float* __restrict__ g,
    const float* __restrict__ b, unsigned short* __restrict__ oh,
    unsigned short* __restrict__ ol) {
  const int t = blockIdx.x, tid = threadIdx.x;
  const float4 v = ((const float4*)(x + (size_t)t * D_MODEL))[tid];
  float s  = v.x + v.y + v.z + v.w;
  float sq = v.x * v.x + v.y * v.y + v.z * v.z + v.w * v.w;
  __shared__ float red[8];
  #pragma unroll
  for (int o = 32; o > 0; o >>= 1) { s += __shfl_down(s, o); sq += __shfl_down(sq, o); }
  if ((tid & 63) == 0) { red[tid >> 6] = s; red[4 + (tid >> 6)] = sq; }
  __syncthreads();
  s  = red[0] + red[1] + red[2] + red[3];
  sq = red[4] + red[5] + red[6] + red[7];
  const float mu = s * (1.0f / D_MODEL);
  const float var = sq * (1.0f / D_MODEL) - mu * mu;
  const float rs = 1.0f / sqrtf(var + LN_EPS);
  const float4 gv = ((const float4*)g)[tid];
  const float4 bv = ((const float4*)b)[tid];
  float4 o;
  o.x = (v.x - mu) * rs * gv.x + bv.x;
  o.y = (v.y - mu) * rs * gv.y + bv.y;
  o.z = (v.z - mu) * rs * gv.z + bv.z;
  o.w = (v.w - mu) * rs * gv.w + bv.w;
  ushort4 hs, ls;
  split16(o.x, hs.x, ls.x); split16(o.y, hs.y, ls.y);
  split16(o.z, hs.z, ls.z); split16(o.w, hs.w, ls.w);
  ((ushort4*)(oh + (size_t)t * D_MODEL))[tid] = hs;
  ((ushort4*)(ol + (size_t)t * D_MODEL))[tid] = ls;
}

// ------- split-f16 MFMA GEMM: C = A @ B^T + bias. A,B^T given as f16 hi/lo. -------
// Grid: x = column tile (fast, shares A-tile), y = row tile.
// MODE 0: C -> f16 hi/lo pair.  MODE 1: C -> f32 with +residual.
template<int MODE>
__global__ __launch_bounds__(256) void gemm_split_kernel(
    const unsigned short* __restrict__ Ah_g, const unsigned short* __restrict__ Al_g,
    const unsigned short* __restrict__ Bh_g, const unsigned short* __restrict__ Bl_g,
    const float* __restrict__ bias, const float* __restrict__ Rres,
    unsigned short* __restrict__ Ch, unsigned short* __restrict__ Cl,
    float* __restrict__ Cf, int M, int N, int K) {
  __shared__ unsigned short LAh[128 * 32], LAl[128 * 32];
  __shared__ unsigned short LBh[128 * 32], LBl[128 * 32];
  const int tid = threadIdx.x, lane = tid & 63, w = tid >> 6;
  const int bm = blockIdx.y * 128, bn = blockIdx.x * 128;
  const int wm = (w >> 1) * 64, wn = (w & 1) * 64;
  f32x4 acc[4][4];
  #pragma unroll
  for (int i = 0; i < 4; ++i)
    #pragma unroll
    for (int j = 0; j < 4; ++j) acc[i][j] = (f32x4){0.f, 0.f, 0.f, 0.f};
  const int lrow16 = lane >> 2, kq8 = (lane & 3) << 3;
  const int r0 = w * 16 + lrow16, r1 = 64 + w * 16 + lrow16;
  const size_t a0 = (size_t)(bm + r0) * K + kq8, a1 = (size_t)(bm + r1) * K + kq8;
  const size_t b0 = (size_t)(bn + r0) * K + kq8, b1 = (size_t)(bn + r1) * K + kq8;
  const int lb0 = (w * 16) * 32, lb1 = (64 + w * 16) * 32;
  const int lrow = lane & 15, lk = (lane >> 4) << 3;
  for (int k0 = 0; k0 < K; k0 += 32) {
    gll16(Ah_g + a0 + k0, &LAh[lb0]); gll16(Ah_g + a1 + k0, &LAh[lb1]);
    gll16(Al_g + a0 + k0, &LAl[lb0]); gll16(Al_g + a1 + k0, &LAl[lb1]);
    gll16(Bh_g + b0 + k0, &LBh[lb0]); gll16(Bh_g + b1 + k0, &LBh[lb1]);
    gll16(Bl_g + b0 + k0, &LBl[lb0]); gll16(Bl_g + b1 + k0, &LBl[lb1]);
    __syncthreads();
    h8 ah[4], al[4], bh[4], bl[4];
    #pragma unroll
    for (int i = 0; i < 4; ++i) {
      ah[i] = *(const h8*)&LAh[(wm + i * 16 + lrow) * 32 + lk];
      al[i] = *(const h8*)&LAl[(wm + i * 16 + lrow) * 32 + lk];
    }
    #pragma unroll
    for (int j = 0; j < 4; ++j) {
      bh[j] = *(const h8*)&LBh[(wn + j * 16 + lrow) * 32 + lk];
      bl[j] = *(const h8*)&LBl[(wn + j * 16 + lrow) * 32 + lk];
    }
    #pragma unroll
    for (int i = 0; i < 4; ++i)
      #pragma unroll
      for (int j = 0; j < 4; ++j) {
        acc[i][j] = __builtin_amdgcn_mfma_f32_16x16x32_f16(ah[i], bh[j], acc[i][j], 0, 0, 0);
        acc[i][j] = __builtin_amdgcn_mfma_f32_16x16x32_f16(ah[i], bl[j], acc[i][j], 0, 0, 0);
        acc[i][j] = __builtin_amdgcn_mfma_f32_16x16x32_f16(al[i], bh[j], acc[i][j], 0, 0, 0);
      }
    __syncthreads();
  }
  const int lc = lane & 15, lr4 = (lane >> 4) * 4;
  #pragma unroll
  for (int i = 0; i < 4; ++i)
    #pragma unroll
    for (int j = 0; j < 4; ++j) {
      const int col = bn + wn + j * 16 + lc;
      const float bsv = bias[col];
      #pragma unroll
      for (int qq = 0; qq < 4; ++qq) {
        const size_t row = (size_t)bm + wm + i * 16 + lr4 + qq;
        const size_t idx = row * N + col;
        const float v = acc[i][j][qq] + bsv;
        if (MODE == 0) {
          unsigned short hi, lo;
          split16(v, hi, lo);
          Ch[idx] = hi; Cl[idx] = lo;
        } else {
          Cf[idx] = v + Rres[idx];
        }
      }
    }
}

// ------- fused QKV split-f16 GEMM: one launch, 24 column tiles (8 per matrix) -------
__global__ __launch_bounds__(256) void gemm_qkv_kernel(
    const unsigned short* __restrict__ Ah_g, const unsigned short* __restrict__ Al_g,
    const unsigned short* __restrict__ BhQ, const unsigned short* __restrict__ BlQ,
    const unsigned short* __restrict__ BhK, const unsigned short* __restrict__ BlK,
    const unsigned short* __restrict__ BhV, const unsigned short* __restrict__ BlV,
    const float* __restrict__ bq, const float* __restrict__ bk, const float* __restrict__ bv,
    unsigned short* __restrict__ Qh, unsigned short* __restrict__ Ql,
    unsigned short* __restrict__ Kh_, unsigned short* __restrict__ Kl_,
    unsigned short* __restrict__ Vh_, unsigned short* __restrict__ Vl_,
    int M, int K) {
  __shared__ unsigned short LAh[128 * 32], LAl[128 * 32];
  __shared__ unsigned short LBh[128 * 32], LBl[128 * 32];
  const int tid = threadIdx.x, lane = tid & 63, w = tid >> 6;
  const int bm = blockIdx.y * 128;
  const int bng = blockIdx.x * 128;
  const int which = bng >> 10;          // block-uniform: 0=Q, 1=K, 2=V
  const int bn = bng & 1023;
  const unsigned short* Bh_g = (which == 0) ? BhQ : ((which == 1) ? BhK : BhV);
  const unsigned short* Bl_g = (which == 0) ? BlQ : ((which == 1) ? BlK : BlV);
  const float* bias = (which == 0) ? bq : ((which == 1) ? bk : bv);
  unsigned short* Ch = (which == 0) ? Qh : ((which == 1) ? Kh_ : Vh_);
  unsigned short* Cl = (which == 0) ? Ql : ((which == 1) ? Kl_ : Vl_);
  const int wm = (w >> 1) * 64, wn = (w & 1) * 64;
  f32x4 acc[4][4];
  #pragma unroll
  for (int i = 0; i < 4; ++i)
    #pragma unroll
    for (int j = 0; j < 4; ++j) acc[i][j] = (f32x4){0.f, 0.f, 0.f, 0.f};
  const int lrow16 = lane >> 2, kq8 = (lane & 3) << 3;
  const int r0 = w * 16 + lrow16, r1 = 64 + w * 16 + lrow16;
  const size_t a0 = (size_t)(bm + r0) * K + kq8, a1 = (size_t)(bm + r1) * K + kq8;
  const size_t b0 = (size_t)(bn + r0) * K + kq8, b1 = (size_t)(bn + r1) * K + kq8;
  const int lb0 = (w * 16) * 32, lb1 = (64 + w * 16) * 32;
  const int lrow = lane & 15, lk = (lane >> 4) << 3;
  for (int k0 = 0; k0 < K; k0 += 32) {
    gll16(Ah_g + a0 + k0, &LAh[lb0]); gll16(Ah_g + a1 + k0, &LAh[lb1]);
    gll16(Al_g + a0 + k0, &LAl[lb0]); gll16(Al_g + a1 + k0, &LAl[lb1]);
    gll16(Bh_g + b0 + k0, &LBh[lb0]); gll16(Bh_g + b1 + k0, &LBh[lb1]);
    gll16(Bl_g + b0 + k0, &LBl[lb0]); gll16(Bl_g + b1 + k0, &LBl[lb1]);
    __syncthreads();
    h8 ah[4], al[4], bh[4], bl[4];
    #pragma unroll
    for (int i = 0; i < 4; ++i) {
      ah[i] = *(const h8*)&LAh[(wm + i * 16 + lrow) * 32 + lk];
      al[i] = *(const h8*)&LAl[(wm + i * 16 + lrow) * 32 + lk];
    }
    #pragma unroll
    for (int j = 0; j < 4; ++j) {
      bh[j] = *(const h8*)&LBh[(wn + j * 16 + lrow) * 32 + lk];
      bl[j] = *(const h8*)&LBl[(wn + j * 16 + lrow) * 32 + lk];
    }
    #pragma unroll
    for (int i = 0; i < 4; ++i)
      #pragma unroll
      for (int j = 0; j < 4; ++j) {
        acc[i][j] = __builtin_amdgcn_mfma_f32_16x16x32_f16(ah[i], bh[j], acc[i][j], 0, 0, 0);
        acc[i][j] = __builtin_amdgcn_mfma_f32_16x16x32_f16(ah[i], bl[j], acc[i][j], 0, 0, 0);
        acc[i][j] = __builtin_amdgcn_mfma_f32_16x16x32_f16(al[i], bh[j], acc[i][j], 0, 0, 0);
      }
    __syncthreads();
  }
  const int lc = lane & 15, lr4 = (lane >> 4) * 4;
  #pragma unroll
  for (int i = 0; i < 4; ++i)
    #pragma unroll
    for (int j = 0; j < 4; ++j) {
      const int col = bn + wn + j * 16 + lc;
      const float bsv = bias[col];
      #pragma unroll
      for (int qq = 0; qq < 4; ++qq) {
        const size_t row = (size_t)bm + wm + i * 16 + lr4 + qq;
        const size_t idx = row * D_MODEL + col;
        const float v = acc[i][j][qq] + bsv;
        unsigned short hi, lo;
        split16(v, hi, lo);
        Ch[idx] = hi; Cl[idx] = lo;
      }
    }
}

// ------------- V transpose (hi+lo fused): [B,T,H*64] f16 -> [B*H, 64, T] f16 -------------
__global__ __launch_bounds__(256) void vtrans_kernel(
    const unsigned short* __restrict__ srch, unsigned short* __restrict__ dsth,
    const unsigned short* __restrict__ srcl, unsigned short* __restrict__ dstl) {
  __shared__ unsigned short tile[64][72];
  const int tid = threadIdx.x;
  const int t0 = blockIdx.x * 64, bh = blockIdx.y;
  const int b = bh >> 4, h = bh & 15;
  const unsigned short* src = blockIdx.z ? srcl : srch;
  unsigned short* dst = blockIdx.z ? dstl : dsth;
  #pragma unroll
  for (int it = 0; it < 2; ++it) {
    const int sg = tid + it * 256;
    const int r = sg >> 3, s = sg & 7;
    *(uint4*)&tile[r][s * 8] =
        *(const uint4*)(src + ((size_t)b * T_SEQ + t0 + r) * D_MODEL + h * HEAD_D + s * 8);
  }
  __syncthreads();
  #pragma unroll
  for (int it = 0; it < 2; ++it) {
    const int sg = tid + it * 256;
    const int d = sg >> 3, s = sg & 7;
    unsigned short v8[8] __attribute__((aligned(16)));
    #pragma unroll
    for (int j = 0; j < 8; ++j) v8[j] = tile[s * 8 + j][d];
    *(uint4*)(dst + ((size_t)bh * HEAD_D + d) * T_SEQ + t0 + s * 8) = *(const uint4*)v8;
  }
}

// ---- causal flash attention v2: 8 waves, QB=128, KB=64, split-f16 MFMA ----
__global__ __launch_bounds__(512) void attn_mfma_kernel(
    const unsigned short* __restrict__ qh_g, const unsigned short* __restrict__ ql_g,
    const unsigned short* __restrict__ kh_g, const unsigned short* __restrict__ kl_g,
    const unsigned short* __restrict__ vth_g, const unsigned short* __restrict__ vtl_g,
    unsigned short* __restrict__ yh, unsigned short* __restrict__ yl) {
  __shared__ unsigned short Kh[64][72], Kl[64][72], Vh[64][72], Vl[64][72];
  __shared__ float Ps[8][16][36];   // per-wave P scratch, one 32-k half at a time
  const int tid = threadIdx.x, lane = tid & 63, w = tid >> 6;       // w = 0..7
  const int g = lane >> 4, c = lane & 15;
  const int qt = (int)gridDim.x - 1 - (int)blockIdx.x;              // big tiles first
  const int bh = blockIdx.y, b = bh >> 4, h = bh & 15;
  const size_t qrow0 = (size_t)b * T_SEQ + qt * 128;
  h8 aqh[2], aql[2];
  {
    const size_t rq = (qrow0 + w * 16 + c) * D_MODEL + h * HEAD_D + g * 8;
    aqh[0] = *(const h8*)(qh_g + rq);
    aqh[1] = *(const h8*)(qh_g + rq + 32);
    aql[0] = *(const h8*)(ql_g + rq);
    aql[1] = *(const h8*)(ql_g + rq + 32);
  }
  f32x4 oacc[4];
  #pragma unroll
  for (int i = 0; i < 4; ++i) oacc[i] = (f32x4){0.f, 0.f, 0.f, 0.f};
  float m[4] = {-3e38f, -3e38f, -3e38f, -3e38f};
  float l[4] = {0.f, 0.f, 0.f, 0.f};
  const int sgr = tid >> 3, sgs = tid & 7;   // 512 threads: one uint4 per buffer each
  const int nkt = 2 * qt + 2;
  for (int kt = 0; kt < nkt; ++kt) {
    const int kv0 = kt * 64;
    __syncthreads();
    {
      const size_t kb = ((size_t)b * T_SEQ + kv0 + sgr) * D_MODEL + h * HEAD_D + sgs * 8;
      const size_t vb = ((size_t)bh * HEAD_D + sgr) * T_SEQ + kv0 + sgs * 8;
      *(uint4*)&Kh[sgr][sgs * 8] = *(const uint4*)(kh_g + kb);
      *(uint4*)&Kl[sgr][sgs * 8] = *(const uint4*)(kl_g + kb);
      *(uint4*)&Vh[sgr][sgs * 8] = *(const uint4*)(vth_g + vb);
      *(uint4*)&Vl[sgr][sgs * 8] = *(const uint4*)(vtl_g + vb);
    }
    __syncthreads();
    f32x4 sv[4];
    __builtin_amdgcn_s_setprio(1);
    #pragma unroll
    for (int nt = 0; nt < 4; ++nt) {
      f32x4 s = {0.f, 0.f, 0.f, 0.f};
      #pragma unroll
      for (int ks = 0; ks < 2; ++ks) {
        const h8 bkh = *(const h8*)&Kh[nt * 16 + c][ks * 32 + g * 8];
        const h8 bkl = *(const h8*)&Kl[nt * 16 + c][ks * 32 + g * 8];
        s = __builtin_amdgcn_mfma_f32_16x16x32_f16(aqh[ks], bkh, s, 0, 0, 0);
        s = __builtin_amdgcn_mfma_f32_16x16x32_f16(aqh[ks], bkl, s, 0, 0, 0);
        s = __builtin_amdgcn_mfma_f32_16x16x32_f16(aql[ks], bkh, s, 0, 0, 0);
      }
      sv[nt] = s;
    }
    __builtin_amdgcn_s_setprio(0);
    float pm[4] = {-3e38f, -3e38f, -3e38f, -3e38f};
    #pragma unroll
    for (int nt = 0; nt < 4; ++nt)
      #pragma unroll
      for (int qq = 0; qq < 4; ++qq) {
        float sval = sv[nt][qq] * 0.125f;
        const int krow = kv0 + nt * 16 + c;
        const int qrow = qt * 128 + w * 16 + g * 4 + qq;
        sval = (krow <= qrow) ? sval : -3.0e38f;
        sv[nt][qq] = sval;
        pm[qq] = fmaxf(pm[qq], sval);
      }
    #pragma unroll
    for (int o = 1; o < 16; o <<= 1)
      #pragma unroll
      for (int qq = 0; qq < 4; ++qq) pm[qq] = fmaxf(pm[qq], __shfl_xor(pm[qq], o));
    float psum[4];
    #pragma unroll
    for (int qq = 0; qq < 4; ++qq) {
      const float mnew = fmaxf(m[qq], pm[qq]);
      const float sc = expf(m[qq] - mnew);
      m[qq] = mnew;
      l[qq] *= sc;
      #pragma unroll
      for (int dt = 0; dt < 4; ++dt) oacc[dt][qq] *= sc;
      psum[qq] = 0.f;
    }
    #pragma unroll
    for (int nt = 0; nt < 4; ++nt)
      #pragma unroll
      for (int qq = 0; qq < 4; ++qq) {
        const float p = expf(sv[nt][qq] - m[qq]);
        sv[nt][qq] = p;
        psum[qq] += p;
      }
    #pragma unroll
    for (int o = 1; o < 16; o <<= 1)
      #pragma unroll
      for (int qq = 0; qq < 4; ++qq) psum[qq] += __shfl_xor(psum[qq], o);
    #pragma unroll
    for (int qq = 0; qq < 4; ++qq) l[qq] += psum[qq];
    #pragma unroll
    for (int half = 0; half < 2; ++half) {
      #pragma unroll
      for (int nt2 = 0; nt2 < 2; ++nt2)
        #pragma unroll
        for (int qq = 0; qq < 4; ++qq)
          Ps[w][g * 4 + qq][nt2 * 16 + c] = sv[half * 2 + nt2][qq];
      const float4 p0 = *(const float4*)&Ps[w][c][g * 8];
      const float4 p1 = *(const float4*)&Ps[w][c][g * 8 + 4];
      const float pv[8] = {p0.x, p0.y, p0.z, p0.w, p1.x, p1.y, p1.z, p1.w};
      h8 pah, pal;
      #pragma unroll
      for (int j = 0; j < 8; ++j) {
        const _Float16 hi = (_Float16)pv[j];
        pah[j] = hi;
        pal[j] = (_Float16)(pv[j] - (float)hi);
      }
      __builtin_amdgcn_s_setprio(1);
      #pragma unroll
      for (int dt = 0; dt < 4; ++dt) {
        const h8 bvh = *(const h8*)&Vh[dt * 16 + c][half * 32 + g * 8];
        const h8 bvl = *(const h8*)&Vl[dt * 16 + c][half * 32 + g * 8];
        oacc[dt] = __builtin_amdgcn_mfma_f32_16x16x32_f16(pah, bvh, oacc[dt], 0, 0, 0);
        oacc[dt] = __builtin_amdgcn_mfma_f32_16x16x32_f16(pah, bvl, oacc[dt], 0, 0, 0);
        oacc[dt] = __builtin_amdgcn_mfma_f32_16x16x32_f16(pal, bvh, oacc[dt], 0, 0, 0);
      }
      __builtin_amdgcn_s_setprio(0);
      if (half == 0) __builtin_amdgcn_sched_barrier(0);
    }
  }
  #pragma unroll
  for (int qq = 0; qq < 4; ++qq) {
    const float inv = 1.0f / l[qq];
    const size_t row = (qrow0 + w * 16 + g * 4 + qq) * D_MODEL + h * HEAD_D;
    #pragma unroll
    for (int dt = 0; dt < 4; ++dt) {
      unsigned short hi, lo;
      split16(oacc[dt][qq] * inv, hi, lo);
      yh[row + dt * 16 + c] = hi;
      yl[row + dt * 16 + c] = lo;
    }
  }
}

// ------------- LN2 + gate logits + top2 routing (f32) -------------
__global__ __launch_bounds__(256) void ln2_route_kernel(
    const float* __restrict__ x1, const float* __restrict__ g,
    const float* __restrict__ b, const float* __restrict__ gW,
    const float* __restrict__ gb, unsigned short* __restrict__ h2b,
    int2* __restrict__ tok_e, float2* __restrict__ tok_w, int* __restrict__ counts) {
  const int t = blockIdx.x, tid = threadIdx.x;
  const float4 v = ((const float4*)(x1 + (size_t)t * D_MODEL))[tid];
  float s  = v.x + v.y + v.z + v.w;
  float sq = v.x * v.x + v.y * v.y + v.z * v.z + v.w * v.w;
  __shared__ float red[8];
  __shared__ float lred[4][8];
  #pragma unroll
  for (int o = 32; o > 0; o >>= 1) { s += __shfl_down(s, o); sq += __shfl_down(sq, o); }
  if ((tid & 63) == 0) { red[tid >> 6] = s; red[4 + (tid >> 6)] = sq; }
  __syncthreads();
  s  = red[0] + red[1] + red[2] + red[3];
  sq = red[4] + red[5] + red[6] + red[7];
  const float mu = s * (1.0f / D_MODEL);
  const float var = sq * (1.0f / D_MODEL) - mu * mu;
  const float rs = 1.0f / sqrtf(var + LN_EPS);
  const float4 gv = ((const float4*)g)[tid];
  const float4 bv = ((const float4*)b)[tid];
  float4 hv;
  hv.x = (v.x - mu) * rs * gv.x + bv.x;
  hv.y = (v.y - mu) * rs * gv.y + bv.y;
  hv.z = (v.z - mu) * rs * gv.z + bv.z;
  hv.w = (v.w - mu) * rs * gv.w + bv.w;
  ushort4 hs;
  hs.x = f2b(hv.x); hs.y = f2b(hv.y); hs.z = f2b(hv.z); hs.w = f2b(hv.w);
  ((ushort4*)(h2b + (size_t)t * D_MODEL))[tid] = hs;
  float lg[8];
  const float* gwr = gW + (size_t)tid * 32;
  #pragma unroll
  for (int e = 0; e < 8; ++e)
    lg[e] = hv.x * gwr[e] + hv.y * gwr[8 + e] +
            hv.z * gwr[16 + e] + hv.w * gwr[24 + e];
  #pragma unroll
  for (int o = 32; o > 0; o >>= 1)
    #pragma unroll
    for (int e = 0; e < 8; ++e) lg[e] += __shfl_down(lg[e], o);
  if ((tid & 63) == 0)
    #pragma unroll
    for (int e = 0; e < 8; ++e) lred[tid >> 6][e] = lg[e];
  __syncthreads();
  if (tid == 0) {
    float L[8];
    #pragma unroll
    for (int e = 0; e < 8; ++e)
      L[e] = lred[0][e] + lred[1][e] + lred[2][e] + lred[3][e] + gb[e];
    int e0 = 0; float v0 = L[0];
    for (int e = 1; e < 8; ++e) if (L[e] > v0) { v0 = L[e]; e0 = e; }
    int e1 = (e0 == 0) ? 1 : 0; float v1 = L[e1];
    for (int e = 0; e < 8; ++e) if (e != e0 && L[e] > v1) { v1 = L[e]; e1 = e; }
    const float ew = expf(v1 - v0);
    const float inv = 1.0f / (1.0f + ew);
    tok_e[t] = make_int2(e0, e1);
    tok_w[t] = make_float2(inv, ew * inv);
    atomicAdd(&counts[e0], 1);
    atomicAdd(&counts[e1], 1);
  }
}

// ------------- routing bookkeeping (128-aligned expert segments) -------------
__global__ void route_offsets_kernel(const int* __restrict__ counts, int* __restrict__ off_al,
    int* __restrict__ ntiles, int* __restrict__ map_e, int* __restrict__ map_row) {
  if (threadIdx.x != 0 || blockIdx.x != 0) return;
  int off = 0, ti = 0;
  for (int e = 0; e < NEXPERT; ++e) {
    off_al[e] = off;
    const int tiles = (counts[e] + 127) >> 7;
    for (int j = 0; j < tiles; ++j) { map_e[ti] = e; map_row[ti] = off + (j << 7); ++ti; }
    off += tiles << 7;
  }
  off_al[NEXPERT] = off;
  ntiles[0] = ti;
}

__global__ __launch_bounds__(256) void place_kernel(
    const int2* __restrict__ tok_e, const int* __restrict__ off_al,
    int* __restrict__ cursors, int* __restrict__ list, int2* __restrict__ tok_pos) {
  const int t = blockIdx.x * 256 + threadIdx.x;
  if (t >= N_TOK) return;
  const int2 te = tok_e[t];
  const int p0 = off_al[te.x] + atomicAdd(&cursors[te.x], 1);
  const int p1 = off_al[te.y] + atomicAdd(&cursors[te.y], 1);
  list[p0] = t; list[p1] = t;
  tok_pos[t] = make_int2(p0, p1);
}

__global__ __launch_bounds__(256) void fill_pad_kernel(
    const int* __restrict__ counts, const int* __restrict__ off_al, int* __restrict__ list) {
  const int i = blockIdx.x * 256 + threadIdx.x;
  const int e = i >> 7, j = i & 127;
  if (e >= NEXPERT) return;
  const int start = off_al[e] + counts[e];
  if (start + j < off_al[e + 1]) list[start + j] = 0;
}

// ------------- f32 -> bf16 transpose (expert weights -> [N][K] layout) -------------
__global__ void transpose_cvt_kernel(
    const float* __restrict__ in, unsigned short* __restrict__ outp, int R, int C) {
  __shared__ float tile[32][33];
  const int e = blockIdx.z;
  const float* I = in + (size_t)e * R * C;
  unsigned short* O = outp + (size_t)e * R * C;
  const int c0 = blockIdx.x * 32, r0 = blockIdx.y * 32;
  const int tx = threadIdx.x, ty = threadIdx.y;
  #pragma unroll
  for (int j = 0; j < 32; j += 8)
    tile[ty + j][tx] = I[(size_t)(r0 + ty + j) * C + c0 + tx];
  __syncthreads();
  #pragma unroll
  for (int j = 0; j < 32; j += 8)
    O[(size_t)(c0 + ty + j) * R + r0 + tx] = f2b(tile[tx][ty + j]);
}

// ------------- f32 -> f16 hi/lo transpose (proj weights -> [N][K]) -------------
__global__ void transpose_cvt_f16_kernel(
    const float* __restrict__ in, unsigned short* __restrict__ oh,
    unsigned short* __restrict__ ol, int R, int C) {
  __shared__ float tile[32][33];
  const int c0 = blockIdx.x * 32, r0 = blockIdx.y * 32;
  const int tx = threadIdx.x, ty = threadIdx.y;
  #pragma unroll
  for (int j = 0; j < 32; j += 8)
    tile[ty + j][tx] = in[(size_t)(r0 + ty + j) * C + c0 + tx];
  __syncthreads();
  #pragma unroll
  for (int j = 0; j < 32; j += 8) {
    unsigned short hi, lo;
    split16(tile[tx][ty + j], hi, lo);
    oh[(size_t)(c0 + ty + j) * R + r0 + tx] = hi;
    ol[(size_t)(c0 + ty + j) * R + r0 + tx] = lo;
  }
}

// ------------- expert GEMM: bf16 MFMA, 128x128 tile, BK=64 (dual 32-col sub-tiles) -------------
// r9 K-loop with two sub-tiles per barrier pair: halves the vmcnt(0)+barrier drain count.
template<int GELU_OUT, int GATHER>
__global__ __launch_bounds__(256) void moe_gemm_kernel(
    const unsigned short* __restrict__ Abase, const unsigned short* __restrict__ Bbase,
    const float* __restrict__ biasBase, unsigned short* __restrict__ midOut,
    float* __restrict__ fOut, const int* __restrict__ list,
    const int* __restrict__ map_e, const int* __restrict__ map_row,
    const int* __restrict__ ntiles_p, int K, int N) {
  const int mt = blockIdx.y;
  if (mt >= ntiles_p[0]) return;
  const int e = map_e[mt];
  const int row0 = map_row[mt];
  const int bn = blockIdx.x * 128;
  const unsigned short* Bp = Bbase + (size_t)e * (size_t)N * (size_t)K;
  const float* bias = biasBase + (size_t)e * N;
  __shared__ unsigned short As[2 * 128 * 32];   // 16 KB
  __shared__ unsigned short Bs[2 * 128 * 32];   // 16 KB
  const int tid = threadIdx.x, lane = tid & 63, wid = tid >> 6;
  const int wm = (wid >> 1) * 64, wn = (wid & 1) * 64;
  f32x4 acc[4][4];
  #pragma unroll
  for (int i = 0; i < 4; ++i)
    #pragma unroll
    for (int j = 0; j < 4; ++j) acc[i][j] = (f32x4){0.f, 0.f, 0.f, 0.f};
  const int lrow16 = lane >> 2, kq8 = (lane & 3) << 3;
  const int r0 = wid * 16 + lrow16, r1 = 64 + wid * 16 + lrow16;
  size_t arow0, arow1;
  if (GATHER) {
    arow0 = (size_t)list[row0 + r0] * (size_t)K + kq8;
    arow1 = (size_t)list[row0 + r1] * (size_t)K + kq8;
  } else {
    arow0 = (size_t)(row0 + r0) * (size_t)K + kq8;
    arow1 = (size_t)(row0 + r1) * (size_t)K + kq8;
  }
  const size_t brow0 = (size_t)(bn + r0) * (size_t)K + kq8;
  const size_t brow1 = (size_t)(bn + r1) * (size_t)K + kq8;
  const int lb0 = (wid * 16) * 32, lb1 = (64 + wid * 16) * 32;
  const int lrow = lane & 15, lk = (lane >> 4) << 3;
  for (int k0 = 0; k0 < K; k0 += 64) {
    gll16(Abase + arow0 + k0, &As[lb0]);
    gll16(Abase + arow1 + k0, &As[lb1]);
    gll16(Bp + brow0 + k0, &Bs[lb0]);
    gll16(Bp + brow1 + k0, &Bs[lb1]);
    gll16(Abase + arow0 + k0 + 32, &As[4096 + lb0]);
    gll16(Abase + arow1 + k0 + 32, &As[4096 + lb1]);
    gll16(Bp + brow0 + k0 + 32, &Bs[4096 + lb0]);
    gll16(Bp + brow1 + k0 + 32, &Bs[4096 + lb1]);
    __syncthreads();
    #pragma unroll
    for (int half = 0; half < 2; ++half) {
      const int boff = half << 12;
      bh8 a[4], b[4];
      #pragma unroll
      for (int i = 0; i < 4; ++i) a[i] = *(const bh8*)&As[boff + (wm + i * 16 + lrow) * 32 + lk];
      #pragma unroll
      for (int j = 0; j < 4; ++j) b[j] = *(const bh8*)&Bs[boff + (wn + j * 16 + lrow) * 32 + lk];
      __builtin_amdgcn_s_setprio(1);
      #pragma unroll
      for (int i = 0; i < 4; ++i)
        #pragma unroll
        for (int j = 0; j < 4; ++j)
          acc[i][j] = __builtin_amdgcn_mfma_f32_16x16x32_bf16(a[i], b[j], acc[i][j], 0, 0, 0);
      __builtin_amdgcn_s_setprio(0);
    }
    __syncthreads();
  }
  const int lc = lane & 15, lr4 = (lane >> 4) * 4;
  #pragma unroll
  for (int i = 0; i < 4; ++i)
    #pragma unroll
    for (int j = 0; j < 4; ++j) {
      const int col = bn + wn + j * 16 + lc;
      const float bsv = bias[col];
      #pragma unroll
      for (int qq = 0; qq < 4; ++qq) {
        const int rowl = wm + i * 16 + lr4 + qq;
        const size_t idx = (size_t)(row0 + rowl) * N + col;
        const float xv = acc[i][j][qq] + bsv;
        if (GELU_OUT) {
          const float gel = 0.5f * xv * (1.0f + erff(xv * 0.70710678118654752f));
          midOut[idx] = f2b(gel);
        } else {
          fOut[idx] = xv;
        }
      }
    }
}

// ------------- combine: out = x1 + w0*y[pos0] + w1*y[pos1], f32 out -------------
__global__ __launch_bounds__(256) void combine_kernel(
    const float* __restrict__ x1, const float* __restrict__ ylist,
    const int2* __restrict__ tok_pos, const float2* __restrict__ tok_w,
    float* __restrict__ outp) {
  const int t = blockIdx.x, tid = threadIdx.x;
  const int2 p = tok_pos[t];
  const float2 w = tok_w[t];
  const float4 a  = ((const float4*)(x1 + (size_t)t * D_MODEL))[tid];
  const float4 y0 = ((const float4*)(ylist + (size_t)p.x * D_MODEL))[tid];
  const float4 y1 = ((const float4*)(ylist + (size_t)p.y * D_MODEL))[tid];
  float4 o;
  o.x = a.x + w.x * y0.x + w.y * y1.x;
  o.y = a.y + w.x * y0.y + w.y * y1.y;
  o.z = a.z + w.x * y0.z + w.y * y1.z;
  o.w = a.w + w.x * y0.w + w.y * y1.w;
  ((float4*)(outp + (size_t)t * D_MODEL))[tid] = o;
}

extern "C" void kernel_launch(void* const* d_in, const int* in_sizes, int n_in,
                              void* d_out, int out_size, void* d_ws, size_t ws_size,
                              hipStream_t stream) {
  const float* x    = (const float*)d_in[0];
  const float* ln1g = (const float*)d_in[1];
  const float* ln1b = (const float*)d_in[2];
  const float* ln2g = (const float*)d_in[3];
  const float* ln2b = (const float*)d_in[4];
  const float* Wq   = (const float*)d_in[5];
  const float* bq   = (const float*)d_in[6];
  const float* Wk   = (const float*)d_in[7];
  const float* bk   = (const float*)d_in[8];
  const float* Wv   = (const float*)d_in[9];
  const float* bv   = (const float*)d_in[10];
  const float* Wp   = (const float*)d_in[11];
  const float* bp   = (const float*)d_in[12];
  const float* gW   = (const float*)d_in[13];
  const float* gb   = (const float*)d_in[14];
  const float* eW1  = (const float*)d_in[15];
  const float* eb1  = (const float*)d_in[16];
  const float* eW2  = (const float*)d_in[17];
  const float* eb2  = (const float*)d_in[18];
  float* out = (float*)d_out;
  (void)in_sizes; (void)n_in; (void)out_size;

  char* wsb = (char*)d_ws;
  size_t off = 0;
  auto alloc = [&](size_t bytes) -> void* {
    void* p = wsb + off;
    off += (bytes + 255) & ~(size_t)255;
    return p;
  };
  int*  counts  = (int*)alloc(32);
  int*  cursors = (int*)alloc(32);
  int*  off_al  = (int*)alloc(64);
  int*  ntiles  = (int*)alloc(64);
  int*  map_e   = (int*)alloc(MAX_TILES * 4);
  int*  map_row = (int*)alloc(MAX_TILES * 4);
  const size_t ctrl_bytes = off;
  int2*   tok_e   = (int2*)alloc((size_t)N_TOK * 8);
  float2* tok_w   = (float2*)alloc((size_t)N_TOK * 8);
  int2*   tok_pos = (int2*)alloc((size_t)N_TOK * 8);
  int*    list    = (int*)alloc((size_t)MAX_ROWS * 4);
  float* x1  = (float*)alloc((size_t)N_TOK * D_MODEL * 4);                       // 32 MB
  unsigned short* h2b = (unsigned short*)alloc((size_t)N_TOK * D_MODEL * 2);     // 16 MB
  unsigned short* W1T = (unsigned short*)alloc((size_t)NEXPERT * D_MODEL * H_MLP * 2);  // 64 MB
  unsigned short* W2T = (unsigned short*)alloc((size_t)NEXPERT * D_MODEL * H_MLP * 2);  // 64 MB
  float* ylist = (float*)alloc((size_t)MAX_ROWS * D_MODEL * 4);                  // 68 MB
  unsigned short* WqTh = (unsigned short*)alloc((size_t)D_MODEL * D_MODEL * 2);
  unsigned short* WqTl = (unsigned short*)alloc((size_t)D_MODEL * D_MODEL * 2);
  unsigned short* WkTh = (unsigned short*)alloc((size_t)D_MODEL * D_MODEL * 2);
  unsigned short* WkTl = (unsigned short*)alloc((size_t)D_MODEL * D_MODEL * 2);
  unsigned short* WvTh = (unsigned short*)alloc((size_t)D_MODEL * D_MODEL * 2);
  unsigned short* WvTl = (unsigned short*)alloc((size_t)D_MODEL * D_MODEL * 2);
  unsigned short* WpTh = (unsigned short*)alloc((size_t)D_MODEL * D_MODEL * 2);
  unsigned short* WpTl = (unsigned short*)alloc((size_t)D_MODEL * D_MODEL * 2);
  // Arena (160 MB): attention-phase f16 buffers alias MoE-phase `mid` (136 MB).
  char* arena = (char*)alloc((size_t)160 * MB);
  unsigned short* h1h = (unsigned short*)(arena);
  unsigned short* h1l = (unsigned short*)(arena + (size_t) 16 * MB);
  unsigned short* qh_ = (unsigned short*)(arena + (size_t) 32 * MB);
  unsigned short* ql_ = (unsigned short*)(arena + (size_t) 48 * MB);
  unsigned short* kh_ = (unsigned short*)(arena + (size_t) 64 * MB);
  unsigned short* kl_ = (unsigned short*)(arena + (size_t) 80 * MB);
  unsigned short* vh_ = (unsigned short*)(arena + (size_t) 96 * MB);
  unsigned short* vl_ = (unsigned short*)(arena + (size_t)112 * MB);
  unsigned short* vth_ = (unsigned short*)(arena + (size_t)128 * MB);
  unsigned short* vtl_ = (unsigned short*)(arena + (size_t)144 * MB);
  unsigned short* yh_ = vh_;   // reuse after vtrans
  unsigned short* yl_ = vl_;
  unsigned short* mid = (unsigned short*)(arena);  // 136 MB, MoE phase
  if (off > ws_size) return;  // ws too small: output stays poisoned -> fails loudly

  hipMemsetAsync(d_ws, 0, ctrl_bytes, stream);

  transpose_cvt_kernel<<<dim3(H_MLP / 32, D_MODEL / 32, NEXPERT), dim3(32, 8), 0, stream>>>(
      eW1, W1T, D_MODEL, H_MLP);
  transpose_cvt_kernel<<<dim3(D_MODEL / 32, H_MLP / 32, NEXPERT), dim3(32, 8), 0, stream>>>(
      eW2, W2T, H_MLP, D_MODEL);
  transpose_cvt_f16_kernel<<<dim3(32, 32), dim3(32, 8), 0, stream>>>(Wq, WqTh, WqTl, D_MODEL, D_MODEL);
  transpose_cvt_f16_kernel<<<dim3(32, 32), dim3(32, 8), 0, stream>>>(Wk, WkTh, WkTl, D_MODEL, D_MODEL);
  transpose_cvt_f16_kernel<<<dim3(32, 32), dim3(32, 8), 0, stream>>>(Wv, WvTh, WvTl, D_MODEL, D_MODEL);
  transpose_cvt_f16_kernel<<<dim3(32, 32), dim3(32, 8), 0, stream>>>(Wp, WpTh, WpTl, D_MODEL, D_MODEL);

  ln1_kernel<<<N_TOK, 256, 0, stream>>>(x, ln1g, ln1b, h1h, h1l);

  gemm_qkv_kernel<<<dim3(24, 64), 256, 0, stream>>>(
      h1h, h1l, WqTh, WqTl, WkTh, WkTl, WvTh, WvTl, bq, bk, bv,
      qh_, ql_, kh_, kl_, vh_, vl_, N_TOK, D_MODEL);

  vtrans_kernel<<<dim3(T_SEQ / 64, (N_TOK / T_SEQ) * NHEADS, 2), 256, 0, stream>>>(
      vh_, vth_, vl_, vtl_);

  attn_mfma_kernel<<<dim3(T_SEQ / 128, (N_TOK / T_SEQ) * NHEADS), 512, 0, stream>>>(
      qh_, ql_, kh_, kl_, vth_, vtl_, yh_, yl_);

  gemm_split_kernel<1><<<dim3(8, 64), 256, 0, stream>>>(
      yh_, yl_, WpTh, WpTl, bp, x, nullptr, nullptr, x1, N_TOK, D_MODEL, D_MODEL);

  ln2_route_kernel<<<N_TOK, 256, 0, stream>>>(x1, ln2g, ln2b, gW, gb, h2b, tok_e, tok_w, counts);
  route_offsets_kernel<<<1, 64, 0, stream>>>(counts, off_al, ntiles, map_e, map_row);
  place_kernel<<<N_TOK / 256, 256, 0, stream>>>(tok_e, off_al, cursors, list, tok_pos);
  fill_pad_kernel<<<4, 256, 0, stream>>>(counts, off_al, list);

  moe_gemm_kernel<1, 1><<<dim3(H_MLP / 128, MAX_TILES), 256, 0, stream>>>(
      h2b, W1T, eb1, mid, nullptr, list, map_e, map_row, ntiles, D_MODEL, H_MLP);
  moe_gemm_kernel<0, 0><<<dim3(D_MODEL / 128, MAX_TILES), 256, 0, stream>>>(
      mid, W2T, eb2, nullptr, ylist, list, map_e, map_row, ntiles, H_MLP, D_MODEL);

  combine_kernel<<<N_TOK, 256, 0, stream>>>(x1, ylist, tok_pos, tok_w, out);
}